// Round 1
// baseline (1202.464 us; speedup 1.0000x reference)
//
#include <hip/hip_runtime.h>

#define N_NODES 50000
#define N_EDGES 800000
#define F_IN 64
#define HID 256
#define N_GRAPHS 128
#define N_OUT 24

// ---------------- CSR build ----------------

__global__ void k_hist(const int* __restrict__ dst, int* __restrict__ deg) {
  int e = blockIdx.x * 256 + threadIdx.x;
  if (e < N_EDGES) atomicAdd(&deg[dst[e]], 1);
}

__global__ void k_count_batch(const int* __restrict__ batch, int* __restrict__ counts) {
  int i = blockIdx.x * 256 + threadIdx.x;
  if (i < N_NODES) atomicAdd(&counts[batch[i]], 1);
}

__global__ __launch_bounds__(1024) void k_scan(const int* __restrict__ deg,
                                               int* __restrict__ rowptr,
                                               int* __restrict__ cursor,
                                               float* __restrict__ deg_inv) {
  __shared__ int s[1024];
  int t = threadIdx.x;
  int carry = 0;
  const int CH = (N_NODES + 1023) / 1024;
  for (int c = 0; c < CH; ++c) {
    int idx = c * 1024 + t;
    int v = (idx < N_NODES) ? deg[idx] : 0;
    s[t] = v;
    __syncthreads();
    for (int off = 1; off < 1024; off <<= 1) {
      int add = (t >= off) ? s[t - off] : 0;
      __syncthreads();
      s[t] += add;
      __syncthreads();
    }
    int excl = s[t] - v;
    if (idx < N_NODES) {
      int rp = carry + excl;
      rowptr[idx] = rp;
      cursor[idx] = rp;
      deg_inv[idx] = 1.0f / fmaxf((float)v, 1.0f);
    }
    carry += s[1023];
    __syncthreads();
  }
  if (t == 0) rowptr[N_NODES] = carry;
}

__global__ void k_scatter(const int* __restrict__ src, const int* __restrict__ dst,
                          int* __restrict__ cursor, int* __restrict__ esrc) {
  int e = blockIdx.x * 256 + threadIdx.x;
  if (e < N_EDGES) {
    int p = atomicAdd(&cursor[dst[e]], 1);
    esrc[p] = src[e];
  }
}

// ---------------- aggregation (gather over CSR), scaled by deg_inv ----------------

__global__ __launch_bounds__(256) void k_agg64(const float* __restrict__ x,
                                               const int* __restrict__ rowptr,
                                               const int* __restrict__ esrc,
                                               const float* __restrict__ deg_inv,
                                               float* __restrict__ out) {
  int node = blockIdx.x * 4 + (threadIdx.x >> 6);
  if (node >= N_NODES) return;
  int lane = threadIdx.x & 63;
  int e0 = rowptr[node], e1 = rowptr[node + 1];
  float acc = 0.f;
  for (int e = e0; e < e1; ++e) {
    int s = esrc[e];
    acc += x[(size_t)s * F_IN + lane];
  }
  out[(size_t)node * F_IN + lane] = acc * deg_inv[node];
}

__global__ __launch_bounds__(256) void k_agg256(const float* __restrict__ x,
                                                const int* __restrict__ rowptr,
                                                const int* __restrict__ esrc,
                                                const float* __restrict__ deg_inv,
                                                float* __restrict__ out) {
  int node = blockIdx.x * 4 + (threadIdx.x >> 6);
  if (node >= N_NODES) return;
  int lane = threadIdx.x & 63;
  int e0 = rowptr[node], e1 = rowptr[node + 1];
  float4 acc = make_float4(0.f, 0.f, 0.f, 0.f);
  for (int e = e0; e < e1; ++e) {
    int s = esrc[e];
    float4 v = *(const float4*)&x[(size_t)s * HID + lane * 4];
    acc.x += v.x; acc.y += v.y; acc.z += v.z; acc.w += v.w;
  }
  float di = deg_inv[node];
  acc.x *= di; acc.y *= di; acc.z *= di; acc.w *= di;
  *(float4*)&out[(size_t)node * HID + lane * 4] = acc;
}

// ---------------- fused two-phase GEMM: out = relu(A1@W1^T + A2@W2^T + b) ----------------
// A1,A2: [M,K] row-major. W1,W2: [N,K] row-major. out: [M,N=256]. Tile 128x128, 8x8/thread.

__global__ __launch_bounds__(256) void k_gemm_fused(
    const float* __restrict__ A1, const float* __restrict__ W1, int K1,
    const float* __restrict__ A2, const float* __restrict__ W2, int K2,
    const float* __restrict__ bias, float* __restrict__ out, int doRelu) {
  const int M = N_NODES, N = HID;
  __shared__ float As[16][132];
  __shared__ float Ws[16][132];
  int t = threadIdx.x;
  int wave = t >> 6, lane = t & 63;
  int lr = lane >> 3, lc = lane & 7;
  int wr = wave >> 1, wc = wave & 1;
  int bm = blockIdx.x, bn = blockIdx.y;
  int trow = wr * 64 + lr * 8;  // within 128-tile
  int tcol = wc * 64 + lc * 8;
  int lrow = t >> 1;            // load: row within tile (0..127)
  int lk = (t & 1) * 8;         // load: k offset 0 or 8

  float acc[8][8];
#pragma unroll
  for (int i = 0; i < 8; ++i)
#pragma unroll
    for (int j = 0; j < 8; ++j) acc[i][j] = 0.f;

#pragma unroll 1
  for (int phase = 0; phase < 2; ++phase) {
    const float* __restrict__ A = phase ? A2 : A1;
    const float* __restrict__ W = phase ? W2 : W1;
    const int K = phase ? K2 : K1;
#pragma unroll 1
    for (int k0 = 0; k0 < K; k0 += 16) {
      int ar = bm * 128 + lrow;
      float4 av0, av1;
      if (ar < M) {
        const float* p = A + (size_t)ar * K + (k0 + lk);
        av0 = *(const float4*)p;
        av1 = *(const float4*)(p + 4);
      } else {
        av0 = make_float4(0.f, 0.f, 0.f, 0.f);
        av1 = av0;
      }
      const float* q = W + (size_t)(bn * 128 + lrow) * K + (k0 + lk);
      float4 wv0 = *(const float4*)q;
      float4 wv1 = *(const float4*)(q + 4);
      __syncthreads();  // previous iteration's LDS reads done
      As[lk + 0][lrow] = av0.x; As[lk + 1][lrow] = av0.y;
      As[lk + 2][lrow] = av0.z; As[lk + 3][lrow] = av0.w;
      As[lk + 4][lrow] = av1.x; As[lk + 5][lrow] = av1.y;
      As[lk + 6][lrow] = av1.z; As[lk + 7][lrow] = av1.w;
      Ws[lk + 0][lrow] = wv0.x; Ws[lk + 1][lrow] = wv0.y;
      Ws[lk + 2][lrow] = wv0.z; Ws[lk + 3][lrow] = wv0.w;
      Ws[lk + 4][lrow] = wv1.x; Ws[lk + 5][lrow] = wv1.y;
      Ws[lk + 6][lrow] = wv1.z; Ws[lk + 7][lrow] = wv1.w;
      __syncthreads();
#pragma unroll
      for (int kk = 0; kk < 16; ++kk) {
        float4 a0 = *(const float4*)&As[kk][trow];
        float4 a1 = *(const float4*)&As[kk][trow + 4];
        float4 w0 = *(const float4*)&Ws[kk][tcol];
        float4 w1 = *(const float4*)&Ws[kk][tcol + 4];
        float a[8] = {a0.x, a0.y, a0.z, a0.w, a1.x, a1.y, a1.z, a1.w};
        float w[8] = {w0.x, w0.y, w0.z, w0.w, w1.x, w1.y, w1.z, w1.w};
#pragma unroll
        for (int i = 0; i < 8; ++i)
#pragma unroll
          for (int j = 0; j < 8; ++j) acc[i][j] = fmaf(a[i], w[j], acc[i][j]);
      }
    }
  }
  int col = bn * 128 + tcol;
  float b[8];
#pragma unroll
  for (int j = 0; j < 8; ++j) b[j] = bias[col + j];
#pragma unroll
  for (int i = 0; i < 8; ++i) {
    int r = bm * 128 + trow + i;
    if (r < M) {
      float v[8];
#pragma unroll
      for (int j = 0; j < 8; ++j) {
        float xv = acc[i][j] + b[j];
        v[j] = doRelu ? fmaxf(xv, 0.f) : xv;
      }
      float* po = out + (size_t)r * N + col;
      *(float4*)po = make_float4(v[0], v[1], v[2], v[3]);
      *(float4*)(po + 4) = make_float4(v[4], v[5], v[6], v[7]);
    }
  }
}

// ---------------- global mean pool (batch is sorted) ----------------

__global__ __launch_bounds__(256) void k_pool(const float* __restrict__ h,
                                              const int* __restrict__ batch,
                                              float* __restrict__ pooled) {
  int f = threadIdx.x;  // 0..255
  int n0 = blockIdx.x * 512;
  if (n0 >= N_NODES) return;
  int n1 = n0 + 512;
  if (n1 > N_NODES) n1 = N_NODES;
  float acc = 0.f;
  int g = batch[n0];
  for (int n = n0; n < n1; ++n) {
    int gn = batch[n];
    if (gn != g) {
      atomicAdd(&pooled[g * HID + f], acc);
      acc = 0.f;
      g = gn;
    }
    acc += h[(size_t)n * HID + f];
  }
  atomicAdd(&pooled[g * HID + f], acc);
}

// ---------------- head: normalize + lin1(relu) + lin2 ----------------

__global__ __launch_bounds__(128) void k_head(const float* __restrict__ pooled,
                                              const int* __restrict__ counts,
                                              const float* __restrict__ w1,
                                              const float* __restrict__ b1,
                                              const float* __restrict__ w2,
                                              const float* __restrict__ b2,
                                              float* __restrict__ out) {
  __shared__ float p[HID];
  __shared__ float g1[HID / 2];
  int g = blockIdx.x, t = threadIdx.x;  // 128 threads
  float inv = 1.f / fmaxf((float)counts[g], 1.f);
  p[t] = pooled[g * HID + t] * inv;
  p[t + 128] = pooled[g * HID + 128 + t] * inv;
  __syncthreads();
  float s = b1[t];
#pragma unroll 4
  for (int k = 0; k < HID; ++k) s = fmaf(p[k], w1[t * HID + k], s);
  g1[t] = fmaxf(s, 0.f);
  __syncthreads();
  if (t < N_OUT) {
    float s2 = b2[t];
#pragma unroll 4
    for (int k = 0; k < HID / 2; ++k) s2 = fmaf(g1[k], w2[t * (HID / 2) + k], s2);
    out[g * N_OUT + t] = s2;
  }
}

// ---------------- launch ----------------

extern "C" void kernel_launch(void* const* d_in, const int* in_sizes, int n_in,
                              void* d_out, int out_size, void* d_ws, size_t ws_size,
                              hipStream_t stream) {
  const float* x      = (const float*)d_in[0];
  const int*   ei     = (const int*)d_in[1];
  const int*   batch  = (const int*)d_in[2];
  const float* w1l    = (const float*)d_in[3];
  const float* b1     = (const float*)d_in[4];
  const float* w1r    = (const float*)d_in[5];
  const float* w2l    = (const float*)d_in[6];
  const float* b2     = (const float*)d_in[7];
  const float* w2r    = (const float*)d_in[8];
  const float* w3l    = (const float*)d_in[9];
  const float* b3     = (const float*)d_in[10];
  const float* w3r    = (const float*)d_in[11];
  const float* lin1_w = (const float*)d_in[12];
  const float* lin1_b = (const float*)d_in[13];
  const float* lin2_w = (const float*)d_in[14];
  const float* lin2_b = (const float*)d_in[15];
  float* out = (float*)d_out;

  const int* src = ei;
  const int* dst = ei + N_EDGES;

  // workspace carve-up (256B aligned)
  size_t off = 0;
  auto carve = [&](size_t bytes) {
    size_t r = off;
    off += (bytes + 255) & ~(size_t)255;
    return r;
  };
  char* ws = (char*)d_ws;
  int*   deg     = (int*)(ws + carve((size_t)N_NODES * 4));
  int*   rowptr  = (int*)(ws + carve((size_t)(N_NODES + 1) * 4));
  int*   cursor  = (int*)(ws + carve((size_t)N_NODES * 4));
  float* deg_inv = (float*)(ws + carve((size_t)N_NODES * 4));
  int*   esrc    = (int*)(ws + carve((size_t)N_EDGES * 4));
  float* agg     = (float*)(ws + carve((size_t)N_NODES * HID * 4));
  float* hA      = (float*)(ws + carve((size_t)N_NODES * HID * 4));
  float* hB      = (float*)(ws + carve((size_t)N_NODES * HID * 4));
  float* pooled  = (float*)(ws + carve((size_t)N_GRAPHS * HID * 4));
  int*   counts  = (int*)(ws + carve((size_t)N_GRAPHS * 4));
  (void)ws_size; (void)n_in; (void)in_sizes; (void)out_size;

  // zero the accumulators
  hipMemsetAsync(deg, 0, (size_t)N_NODES * 4, stream);
  hipMemsetAsync(counts, 0, (size_t)N_GRAPHS * 4, stream);
  hipMemsetAsync(pooled, 0, (size_t)N_GRAPHS * HID * 4, stream);

  const int EB = (N_EDGES + 255) / 256;
  const int NB = (N_NODES + 255) / 256;

  k_hist<<<EB, 256, 0, stream>>>(dst, deg);
  k_count_batch<<<NB, 256, 0, stream>>>(batch, counts);
  k_scan<<<1, 1024, 0, stream>>>(deg, rowptr, cursor, deg_inv);
  k_scatter<<<EB, 256, 0, stream>>>(src, dst, cursor, esrc);

  dim3 ggrid((N_NODES + 127) / 128, HID / 128);

  // layer 1
  k_agg64<<<(N_NODES + 3) / 4, 256, 0, stream>>>(x, rowptr, esrc, deg_inv, agg);
  k_gemm_fused<<<ggrid, 256, 0, stream>>>(agg, w1l, F_IN, x, w1r, F_IN, b1, hA, 1);
  // layer 2
  k_agg256<<<(N_NODES + 3) / 4, 256, 0, stream>>>(hA, rowptr, esrc, deg_inv, agg);
  k_gemm_fused<<<ggrid, 256, 0, stream>>>(agg, w2l, HID, hA, w2r, HID, b2, hB, 1);
  // layer 3
  k_agg256<<<(N_NODES + 3) / 4, 256, 0, stream>>>(hB, rowptr, esrc, deg_inv, agg);
  k_gemm_fused<<<ggrid, 256, 0, stream>>>(agg, w3l, HID, hB, w3r, HID, b3, hA, 1);

  // pool + head
  k_pool<<<(N_NODES + 511) / 512, 256, 0, stream>>>(hA, batch, pooled);
  k_head<<<N_GRAPHS, 128, 0, stream>>>(pooled, counts, lin1_w, lin1_b, lin2_w, lin2_b, out);
}

// Round 2
// 881.962 us; speedup vs baseline: 1.3634x; 1.3634x over previous
//
#include <hip/hip_runtime.h>

#define N_NODES 50000
#define M_PAD   50048   // padded rows so global_load_lds never reads past buffers
#define N_EDGES 800000
#define F_IN 64
#define HID 256
#define N_GRAPHS 128
#define N_OUT 24

typedef unsigned short ushort_t;
typedef __attribute__((ext_vector_type(8))) unsigned short us8;
typedef __attribute__((ext_vector_type(4))) unsigned short us4;
typedef __attribute__((ext_vector_type(8))) __bf16 bf16x8;
typedef __attribute__((ext_vector_type(4))) float f32x4;

__device__ __forceinline__ unsigned short f2bf(float f) {
  unsigned u = __builtin_bit_cast(unsigned, f);
  return (unsigned short)((u + 0x7fffu + ((u >> 16) & 1u)) >> 16);
}
__device__ __forceinline__ float bf2f(unsigned short h) {
  return __builtin_bit_cast(float, (unsigned)h << 16);
}

__device__ __forceinline__ f32x4 mfma_bf16(us8 a, us8 b, f32x4 c) {
  return __builtin_amdgcn_mfma_f32_16x16x32_bf16(
      __builtin_bit_cast(bf16x8, a), __builtin_bit_cast(bf16x8, b), c, 0, 0, 0);
}

__device__ __forceinline__ void gload16(const ushort_t* g, ushort_t* l) {
  __builtin_amdgcn_global_load_lds(
      (const __attribute__((address_space(1))) void*)g,
      (__attribute__((address_space(3))) void*)l, 16, 0, 0);
}

// ---------------- CSR build ----------------

__global__ void k_hist(const int* __restrict__ dst, int* __restrict__ deg) {
  int e = blockIdx.x * 256 + threadIdx.x;
  if (e < N_EDGES) atomicAdd(&deg[dst[e]], 1);
}

__global__ void k_count_batch(const int* __restrict__ batch, int* __restrict__ counts) {
  int i = blockIdx.x * 256 + threadIdx.x;
  if (i < N_NODES) atomicAdd(&counts[batch[i]], 1);
}

__global__ __launch_bounds__(1024) void k_scan1(const int* __restrict__ deg,
                                                int* __restrict__ rowptr,
                                                int* __restrict__ partial) {
  __shared__ int s[1024];
  int t = threadIdx.x;
  int idx = blockIdx.x * 1024 + t;
  int v = (idx < N_NODES) ? deg[idx] : 0;
  s[t] = v;
  __syncthreads();
  for (int off = 1; off < 1024; off <<= 1) {
    int a = (t >= off) ? s[t - off] : 0;
    __syncthreads();
    s[t] += a;
    __syncthreads();
  }
  if (idx < N_NODES) rowptr[idx] = s[t] - v;  // local exclusive
  if (t == 1023) partial[blockIdx.x] = s[1023];
}

__global__ void k_scan2(int* __restrict__ partial, int* __restrict__ rowptr) {
  __shared__ int s[64];
  int t = threadIdx.x;  // 64 threads, 1 block
  const int NB = (N_NODES + 1023) / 1024;
  int v = (t < NB) ? partial[t] : 0;
  s[t] = v;
  __syncthreads();
  for (int off = 1; off < 64; off <<= 1) {
    int a = (t >= off) ? s[t - off] : 0;
    __syncthreads();
    s[t] += a;
    __syncthreads();
  }
  if (t < NB) partial[t] = s[t] - v;  // exclusive block offsets
  if (t == NB - 1) rowptr[N_NODES] = s[t];
}

__global__ __launch_bounds__(1024) void k_scan3(const int* __restrict__ deg,
                                                const int* __restrict__ partial,
                                                int* __restrict__ rowptr,
                                                int* __restrict__ cursor,
                                                float* __restrict__ deg_inv) {
  int idx = blockIdx.x * 1024 + threadIdx.x;
  if (idx < N_NODES) {
    int rp = rowptr[idx] + partial[blockIdx.x];
    rowptr[idx] = rp;
    cursor[idx] = rp;
    deg_inv[idx] = 1.0f / fmaxf((float)deg[idx], 1.0f);
  }
}

__global__ void k_scatter(const int* __restrict__ src, const int* __restrict__ dst,
                          int* __restrict__ cursor, int* __restrict__ esrc) {
  int e = blockIdx.x * 256 + threadIdx.x;
  if (e < N_EDGES) {
    int p = atomicAdd(&cursor[dst[e]], 1);
    esrc[p] = src[e];
  }
}

// ---------------- split/swizzle prep kernels ----------------
// Swizzled layout: row r, k-block kb (8 bf16) stored at kb ^ (r&7) (low 3 bits XOR).

__global__ void k_prep_x(const float* __restrict__ x, ushort_t* __restrict__ xhi,
                         ushort_t* __restrict__ xlo) {
  int g = blockIdx.x * 256 + threadIdx.x;  // granule id
  if (g >= N_NODES * 8) return;
  int row = g >> 3, kb = g & 7;
  const float* p = x + (size_t)row * F_IN + kb * 8;
  union { unsigned short s[8]; us8 v; } H, L;
#pragma unroll
  for (int i = 0; i < 8; ++i) {
    float f = p[i];
    H.s[i] = f2bf(f);
    L.s[i] = f2bf(f - bf2f(H.s[i]));
  }
  size_t ob = (size_t)row * F_IN + (size_t)((kb ^ (row & 7)) << 3);
  *(us8*)&xhi[ob] = H.v;
  *(us8*)&xlo[ob] = L.v;
}

__global__ void k_prep_w(const float* __restrict__ wl, const float* __restrict__ wr,
                         ushort_t* __restrict__ dhi, ushort_t* __restrict__ dlo,
                         int kgsh /* log2(Kg) */) {
  const int Kg = 1 << kgsh;
  const float* src = blockIdx.y ? wr : wl;
  int g = blockIdx.x * 256 + threadIdx.x;
  if (g >= 256 * Kg) return;
  int row = g >> kgsh, kb = g & (Kg - 1);
  const float* p = src + (size_t)row * (Kg * 8) + kb * 8;
  union { unsigned short s[8]; us8 v; } H, L;
#pragma unroll
  for (int i = 0; i < 8; ++i) {
    float f = p[i];
    H.s[i] = f2bf(f);
    L.s[i] = f2bf(f - bf2f(H.s[i]));
  }
  size_t ob = ((size_t)(blockIdx.y * 256 + row) * Kg + (kb ^ (row & 7))) * 8;
  *(us8*)&dhi[ob] = H.v;
  *(us8*)&dlo[ob] = L.v;
}

// ---------------- aggregation (gather over CSR) -> split+swizzled bf16 ----------------

__global__ __launch_bounds__(256) void k_agg64s(const float* __restrict__ x,
                                                const int* __restrict__ rowptr,
                                                const int* __restrict__ esrc,
                                                const float* __restrict__ deg_inv,
                                                ushort_t* __restrict__ ohi,
                                                ushort_t* __restrict__ olo) {
  int node = blockIdx.x * 4 + (threadIdx.x >> 6);
  if (node >= N_NODES) return;
  int lane = threadIdx.x & 63;
  int e0 = rowptr[node], e1 = rowptr[node + 1];
  float acc = 0.f;
  for (int e = e0; e < e1; ++e) acc += x[(size_t)esrc[e] * F_IN + lane];
  acc *= deg_inv[node];
  unsigned short hi = f2bf(acc);
  unsigned short lo = f2bf(acc - bf2f(hi));
  size_t ob = (size_t)node * F_IN + (size_t)((((lane >> 3) ^ (node & 7)) << 3) + (lane & 7));
  ohi[ob] = hi;
  olo[ob] = lo;
}

__global__ __launch_bounds__(256) void k_agg256s(const ushort_t* __restrict__ hhi,
                                                 const ushort_t* __restrict__ hlo,
                                                 const int* __restrict__ rowptr,
                                                 const int* __restrict__ esrc,
                                                 const float* __restrict__ deg_inv,
                                                 ushort_t* __restrict__ ohi,
                                                 ushort_t* __restrict__ olo) {
  int node = blockIdx.x * 4 + (threadIdx.x >> 6);
  if (node >= N_NODES) return;
  int lane = threadIdx.x & 63;
  int kb = lane >> 1;          // k-block 0..31
  int sub = (lane & 1) << 2;   // 0 or 4
  int e0 = rowptr[node], e1 = rowptr[node + 1];
  float a0 = 0.f, a1 = 0.f, a2 = 0.f, a3 = 0.f;
  for (int e = e0; e < e1; ++e) {
    int s = esrc[e];
    size_t base = (size_t)s * HID + (size_t)(((kb ^ (s & 7)) << 3) + sub);
    us4 hv = *(const us4*)&hhi[base];
    us4 lv = *(const us4*)&hlo[base];
    a0 += bf2f(hv[0]) + bf2f(lv[0]);
    a1 += bf2f(hv[1]) + bf2f(lv[1]);
    a2 += bf2f(hv[2]) + bf2f(lv[2]);
    a3 += bf2f(hv[3]) + bf2f(lv[3]);
  }
  float di = deg_inv[node];
  a0 *= di; a1 *= di; a2 *= di; a3 *= di;
  size_t ob = (size_t)node * HID + (size_t)(((kb ^ (node & 7)) << 3) + sub);
  float vals[4] = {a0, a1, a2, a3};
#pragma unroll
  for (int i = 0; i < 4; ++i) {
    unsigned short hi = f2bf(vals[i]);
    ohi[ob + i] = hi;
    olo[ob + i] = f2bf(vals[i] - bf2f(hi));
  }
}

// ---------------- split-bf16 MFMA GEMM ----------------
// out = relu(A1@W1^T + A2@W2^T + b). A: [M_PAD, K] pre-split/swizzled hi/lo bf16.
// W: [256, K] pre-split/swizzled hi/lo bf16. Tile 128x128, BK=64, 4 waves.
// mode 0: store h as split+swizzled bf16 (HID cols). mode 1: store fp32.

__global__ __launch_bounds__(256) void k_gemm_mfma(
    const ushort_t* __restrict__ a1h, const ushort_t* __restrict__ a1l,
    const ushort_t* __restrict__ w1h, const ushort_t* __restrict__ w1l, int k1g,
    const ushort_t* __restrict__ a2h, const ushort_t* __restrict__ a2l,
    const ushort_t* __restrict__ w2h, const ushort_t* __restrict__ w2l, int k2g,
    const float* __restrict__ bias, ushort_t* __restrict__ ohi,
    ushort_t* __restrict__ olo, float* __restrict__ ofp, int mode) {
  __shared__ __align__(16) ushort_t lds[4][8192];  // Ahi Alo Whi Wlo, 16KB each

  int t = threadIdx.x;
  int wv = t >> 6, lane = t & 63;
  int wr = wv >> 1, wc = wv & 1;
  int fr = lane & 15, kq = lane >> 4;
  int bm = blockIdx.x, bn = blockIdx.y;
  int rowA0 = bm * 128, rowW0 = bn * 128;

  f32x4 acc[4][4];
#pragma unroll
  for (int m = 0; m < 4; ++m)
#pragma unroll
    for (int n = 0; n < 4; ++n) acc[m][n] = (f32x4)0.f;

  const int ns1 = k1g >> 3, ns2 = k2g >> 3;
  const int lrow = wv * 32 + (lane >> 3);  // staging row base (+ i*8)
  const int lj = lane & 7;                 // staging k-granule within step

  for (int s = 0; s < ns1 + ns2; ++s) {
    const bool p2 = (s >= ns1);
    const ushort_t* Ah = p2 ? a2h : a1h;
    const ushort_t* Al = p2 ? a2l : a1l;
    const ushort_t* Wh = p2 ? w2h : w1h;
    const ushort_t* Wl = p2 ? w2l : w1l;
    const int Kg = p2 ? k2g : k1g;
    const int ksg = (p2 ? (s - ns1) : s) * 8;

#pragma unroll
    for (int i = 0; i < 4; ++i) {
      int row = lrow + i * 8;
      size_t offA = ((size_t)(rowA0 + row) * Kg + ksg + lj) * 8;
      size_t offW = ((size_t)(rowW0 + row) * Kg + ksg + lj) * 8;
      int lo = (wv * 256 + i * 64) * 8;
      gload16(Ah + offA, &lds[0][lo]);
      gload16(Al + offA, &lds[1][lo]);
      gload16(Wh + offW, &lds[2][lo]);
      gload16(Wl + offW, &lds[3][lo]);
    }
    __syncthreads();  // drains vmcnt -> LDS tile ready

#pragma unroll
    for (int kc = 0; kc < 2; ++kc) {
      us8 ah[4], al[4], bh[4], bl[4];
      int kg = kc * 4 + kq;
      int swk = (kg ^ (fr & 7)) << 3;
#pragma unroll
      for (int m = 0; m < 4; ++m) {
        int off = ((wr * 64 + m * 16 + fr) << 6) + swk;
        ah[m] = *(const us8*)&lds[0][off];
        al[m] = *(const us8*)&lds[1][off];
      }
#pragma unroll
      for (int n = 0; n < 4; ++n) {
        int off = ((wc * 64 + n * 16 + fr) << 6) + swk;
        bh[n] = *(const us8*)&lds[2][off];
        bl[n] = *(const us8*)&lds[3][off];
      }
#pragma unroll
      for (int m = 0; m < 4; ++m)
#pragma unroll
        for (int n = 0; n < 4; ++n) {
          acc[m][n] = mfma_bf16(ah[m], bh[n], acc[m][n]);
          acc[m][n] = mfma_bf16(ah[m], bl[n], acc[m][n]);
          acc[m][n] = mfma_bf16(al[m], bh[n], acc[m][n]);
        }
    }
    __syncthreads();  // all reads done before next stage overwrites
  }

  // epilogue: C/D map col=lane&15, row=(lane>>4)*4+reg (m89-verified)
#pragma unroll
  for (int n = 0; n < 4; ++n) {
    int colg = bn * 128 + wc * 64 + n * 16 + fr;
    float bv = bias[colg];
#pragma unroll
    for (int m = 0; m < 4; ++m) {
      f32x4 v = acc[m][n];
      int rowb = bm * 128 + wr * 64 + m * 16 + kq * 4;
#pragma unroll
      for (int r = 0; r < 4; ++r) {
        int rowg = rowb + r;
        if (rowg < N_NODES) {
          float h = fmaxf(v[r] + bv, 0.f);
          if (mode == 0) {
            unsigned short hi = f2bf(h);
            unsigned short lo = f2bf(h - bf2f(hi));
            int kbs = (colg >> 3) ^ (rowg & 7);
            size_t ob = (size_t)rowg * HID + (size_t)((kbs << 3) + (colg & 7));
            ohi[ob] = hi;
            olo[ob] = lo;
          } else {
            ofp[(size_t)rowg * HID + colg] = h;
          }
        }
      }
    }
  }
}

// ---------------- global mean pool (batch sorted) ----------------

__global__ __launch_bounds__(256) void k_pool(const float* __restrict__ h,
                                              const int* __restrict__ batch,
                                              float* __restrict__ pooled) {
  int f = threadIdx.x;
  int n0 = blockIdx.x * 512;
  if (n0 >= N_NODES) return;
  int n1 = n0 + 512;
  if (n1 > N_NODES) n1 = N_NODES;
  float acc = 0.f;
  int g = batch[n0];
  for (int n = n0; n < n1; ++n) {
    int gn = batch[n];
    if (gn != g) {
      atomicAdd(&pooled[g * HID + f], acc);
      acc = 0.f;
      g = gn;
    }
    acc += h[(size_t)n * HID + f];
  }
  atomicAdd(&pooled[g * HID + f], acc);
}

// ---------------- head ----------------

__global__ __launch_bounds__(128) void k_head(const float* __restrict__ pooled,
                                              const int* __restrict__ counts,
                                              const float* __restrict__ w1,
                                              const float* __restrict__ b1,
                                              const float* __restrict__ w2,
                                              const float* __restrict__ b2,
                                              float* __restrict__ out) {
  __shared__ float p[HID];
  __shared__ float g1[HID / 2];
  int g = blockIdx.x, t = threadIdx.x;
  float inv = 1.f / fmaxf((float)counts[g], 1.f);
  p[t] = pooled[g * HID + t] * inv;
  p[t + 128] = pooled[g * HID + 128 + t] * inv;
  __syncthreads();
  float s = b1[t];
#pragma unroll 4
  for (int k = 0; k < HID; ++k) s = fmaf(p[k], w1[t * HID + k], s);
  g1[t] = fmaxf(s, 0.f);
  __syncthreads();
  if (t < N_OUT) {
    float s2 = b2[t];
#pragma unroll 4
    for (int k = 0; k < HID / 2; ++k) s2 = fmaf(g1[k], w2[t * (HID / 2) + k], s2);
    out[g * N_OUT + t] = s2;
  }
}

// ---------------- launch ----------------

extern "C" void kernel_launch(void* const* d_in, const int* in_sizes, int n_in,
                              void* d_out, int out_size, void* d_ws, size_t ws_size,
                              hipStream_t stream) {
  const float* x      = (const float*)d_in[0];
  const int*   ei     = (const int*)d_in[1];
  const int*   batch  = (const int*)d_in[2];
  const float* w1lw   = (const float*)d_in[3];
  const float* b1     = (const float*)d_in[4];
  const float* w1rw   = (const float*)d_in[5];
  const float* w2lw   = (const float*)d_in[6];
  const float* b2     = (const float*)d_in[7];
  const float* w2rw   = (const float*)d_in[8];
  const float* w3lw   = (const float*)d_in[9];
  const float* b3     = (const float*)d_in[10];
  const float* w3rw   = (const float*)d_in[11];
  const float* lin1_w = (const float*)d_in[12];
  const float* lin1_b = (const float*)d_in[13];
  const float* lin2_w = (const float*)d_in[14];
  const float* lin2_b = (const float*)d_in[15];
  float* out = (float*)d_out;

  const int* srcIdx = ei;
  const int* dstIdx = ei + N_EDGES;

  size_t off = 0;
  auto carve = [&](size_t bytes) {
    size_t r = off;
    off += (bytes + 255) & ~(size_t)255;
    return r;
  };
  char* ws = (char*)d_ws;
  int*      deg     = (int*)(ws + carve((size_t)N_NODES * 4));
  int*      rowptr  = (int*)(ws + carve((size_t)(N_NODES + 1) * 4));
  int*      cursor  = (int*)(ws + carve((size_t)N_NODES * 4));
  float*    deg_inv = (float*)(ws + carve((size_t)N_NODES * 4));
  int*      esrc    = (int*)(ws + carve((size_t)N_EDGES * 4));
  int*      partial = (int*)(ws + carve(64 * 4));
  ushort_t* xhi     = (ushort_t*)(ws + carve((size_t)M_PAD * F_IN * 2));
  ushort_t* xlo     = (ushort_t*)(ws + carve((size_t)M_PAD * F_IN * 2));
  ushort_t* agghi   = (ushort_t*)(ws + carve((size_t)M_PAD * HID * 2));
  ushort_t* agglo   = (ushort_t*)(ws + carve((size_t)M_PAD * HID * 2));
  char*     h1blk   = ws + carve((size_t)M_PAD * HID * 4);  // h1 pair OR h3 fp32
  ushort_t* h1hi    = (ushort_t*)h1blk;
  ushort_t* h1lo    = (ushort_t*)(h1blk + (size_t)M_PAD * HID * 2);
  float*    h3      = (float*)h1blk;  // alias (h1 dead before gemm3 writes)
  ushort_t* h2hi    = (ushort_t*)(ws + carve((size_t)M_PAD * HID * 2));
  ushort_t* h2lo    = (ushort_t*)(ws + carve((size_t)M_PAD * HID * 2));
  ushort_t* w1hi    = (ushort_t*)(ws + carve((size_t)2 * 256 * F_IN * 2));
  ushort_t* w1lo    = (ushort_t*)(ws + carve((size_t)2 * 256 * F_IN * 2));
  ushort_t* w2hi    = (ushort_t*)(ws + carve((size_t)2 * 256 * HID * 2));
  ushort_t* w2lo    = (ushort_t*)(ws + carve((size_t)2 * 256 * HID * 2));
  ushort_t* w3hi    = (ushort_t*)(ws + carve((size_t)2 * 256 * HID * 2));
  ushort_t* w3lo    = (ushort_t*)(ws + carve((size_t)2 * 256 * HID * 2));
  float*    pooled  = (float*)(ws + carve((size_t)N_GRAPHS * HID * 4));
  int*      counts  = (int*)(ws + carve((size_t)N_GRAPHS * 4));
  (void)ws_size; (void)n_in; (void)in_sizes; (void)out_size;

  hipMemsetAsync(deg, 0, (size_t)N_NODES * 4, stream);
  hipMemsetAsync(counts, 0, (size_t)N_GRAPHS * 4, stream);
  hipMemsetAsync(pooled, 0, (size_t)N_GRAPHS * HID * 4, stream);

  const int EB = (N_EDGES + 255) / 256;
  const int NB = (N_NODES + 255) / 256;
  const int SB = (N_NODES + 1023) / 1024;  // 49

  k_hist<<<EB, 256, 0, stream>>>(dstIdx, deg);
  k_count_batch<<<NB, 256, 0, stream>>>(batch, counts);
  k_scan1<<<SB, 1024, 0, stream>>>(deg, rowptr, partial);
  k_scan2<<<1, 64, 0, stream>>>(partial, rowptr);
  k_scan3<<<SB, 1024, 0, stream>>>(deg, partial, rowptr, cursor, deg_inv);
  k_scatter<<<EB, 256, 0, stream>>>(srcIdx, dstIdx, cursor, esrc);

  // weight / input split+swizzle prep
  k_prep_x<<<(N_NODES * 8 + 255) / 256, 256, 0, stream>>>(x, xhi, xlo);
  k_prep_w<<<dim3(8, 2), 256, 0, stream>>>(w1lw, w1rw, w1hi, w1lo, 3);
  k_prep_w<<<dim3(32, 2), 256, 0, stream>>>(w2lw, w2rw, w2hi, w2lo, 5);
  k_prep_w<<<dim3(32, 2), 256, 0, stream>>>(w3lw, w3rw, w3hi, w3lo, 5);

  dim3 ggrid((N_NODES + 127) / 128, 2);
  const int AB = N_NODES / 4;  // 12500

  // layer 1: relu(agg(x)@w1l^T + x@w1r^T + b1)
  k_agg64s<<<AB, 256, 0, stream>>>(x, rowptr, esrc, deg_inv, agghi, agglo);
  k_gemm_mfma<<<ggrid, 256, 0, stream>>>(agghi, agglo, w1hi, w1lo, 8,
                                         xhi, xlo, w1hi + 256 * F_IN, w1lo + 256 * F_IN, 8,
                                         b1, h1hi, h1lo, nullptr, 0);
  // layer 2
  k_agg256s<<<AB, 256, 0, stream>>>(h1hi, h1lo, rowptr, esrc, deg_inv, agghi, agglo);
  k_gemm_mfma<<<ggrid, 256, 0, stream>>>(agghi, agglo, w2hi, w2lo, 32,
                                         h1hi, h1lo, w2hi + 256 * HID, w2lo + 256 * HID, 32,
                                         b2, h2hi, h2lo, nullptr, 0);
  // layer 3 (fp32 out for pooling; h3 aliases h1 which is no longer read)
  k_agg256s<<<AB, 256, 0, stream>>>(h2hi, h2lo, rowptr, esrc, deg_inv, agghi, agglo);
  k_gemm_mfma<<<ggrid, 256, 0, stream>>>(agghi, agglo, w3hi, w3lo, 32,
                                         h2hi, h2lo, w3hi + 256 * HID, w3lo + 256 * HID, 32,
                                         b3, nullptr, nullptr, h3, 1);

  k_pool<<<(N_NODES + 511) / 512, 256, 0, stream>>>(h3, batch, pooled);
  k_head<<<N_GRAPHS, 128, 0, stream>>>(pooled, counts, lin1_w, lin1_b, lin2_w, lin2_b, out);
}

// Round 3
// 752.343 us; speedup vs baseline: 1.5983x; 1.1723x over previous
//
#include <hip/hip_runtime.h>

#define N_NODES 50000
#define M_PAD   50048   // padded rows so global_load_lds never reads past buffers
#define N_EDGES 800000
#define F_IN 64
#define HID 256
#define N_GRAPHS 128
#define N_OUT 24

typedef unsigned short ushort_t;
typedef __attribute__((ext_vector_type(8))) unsigned short us8;
typedef __attribute__((ext_vector_type(8))) __bf16 bf16x8;
typedef __attribute__((ext_vector_type(4))) float f32x4;

__device__ __forceinline__ unsigned short f2bf(float f) {
  unsigned u = __builtin_bit_cast(unsigned, f);
  return (unsigned short)((u + 0x7fffu + ((u >> 16) & 1u)) >> 16);
}
__device__ __forceinline__ float bf2f(unsigned short h) {
  return __builtin_bit_cast(float, (unsigned)h << 16);
}

__device__ __forceinline__ f32x4 mfma_bf16(us8 a, us8 b, f32x4 c) {
  return __builtin_amdgcn_mfma_f32_16x16x32_bf16(
      __builtin_bit_cast(bf16x8, a), __builtin_bit_cast(bf16x8, b), c, 0, 0, 0);
}

__device__ __forceinline__ void gload16(const ushort_t* g, ushort_t* l) {
  __builtin_amdgcn_global_load_lds(
      (const __attribute__((address_space(1))) void*)g,
      (__attribute__((address_space(3))) void*)l, 16, 0, 0);
}

// ---------------- CSR build ----------------

__global__ void k_hist(const int* __restrict__ dst, const int* __restrict__ batch,
                       int* __restrict__ deg, int* __restrict__ counts) {
  int e = blockIdx.x * 256 + threadIdx.x;
  if (e < N_EDGES) atomicAdd(&deg[dst[e]], 1);
  if (e < N_NODES) atomicAdd(&counts[batch[e]], 1);
}

__global__ __launch_bounds__(1024) void k_scan1(const int* __restrict__ deg,
                                                int* __restrict__ rowptr,
                                                int* __restrict__ partial) {
  __shared__ int s[1024];
  int t = threadIdx.x;
  int idx = blockIdx.x * 1024 + t;
  int v = (idx < N_NODES) ? deg[idx] : 0;
  s[t] = v;
  __syncthreads();
  for (int off = 1; off < 1024; off <<= 1) {
    int a = (t >= off) ? s[t - off] : 0;
    __syncthreads();
    s[t] += a;
    __syncthreads();
  }
  if (idx < N_NODES) rowptr[idx] = s[t] - v;  // local exclusive
  if (t == 1023) partial[blockIdx.x] = s[1023];
}

__global__ void k_scan2(int* __restrict__ partial, int* __restrict__ rowptr) {
  __shared__ int s[64];
  int t = threadIdx.x;  // 64 threads, 1 block
  const int NB = (N_NODES + 1023) / 1024;
  int v = (t < NB) ? partial[t] : 0;
  s[t] = v;
  __syncthreads();
  for (int off = 1; off < 64; off <<= 1) {
    int a = (t >= off) ? s[t - off] : 0;
    __syncthreads();
    s[t] += a;
    __syncthreads();
  }
  if (t < NB) partial[t] = s[t] - v;  // exclusive block offsets
  if (t == NB - 1) rowptr[N_NODES] = s[t];
}

__global__ __launch_bounds__(1024) void k_scan3(const int* __restrict__ deg,
                                                const int* __restrict__ partial,
                                                int* __restrict__ rowptr,
                                                int* __restrict__ cursor,
                                                float* __restrict__ deg_inv) {
  int idx = blockIdx.x * 1024 + threadIdx.x;
  if (idx < N_NODES) {
    int rp = rowptr[idx] + partial[blockIdx.x];
    rowptr[idx] = rp;
    cursor[idx] = rp;
    deg_inv[idx] = 1.0f / fmaxf((float)deg[idx], 1.0f);
  }
}

__global__ void k_scatter(const int* __restrict__ src, const int* __restrict__ dst,
                          int* __restrict__ cursor, int* __restrict__ esrc) {
  int e = blockIdx.x * 256 + threadIdx.x;
  if (e < N_EDGES) {
    int p = atomicAdd(&cursor[dst[e]], 1);
    esrc[p] = src[e];
  }
}

__global__ void k_gofs(const int* __restrict__ counts, int* __restrict__ gofs) {
  __shared__ int s[N_GRAPHS];
  int t = threadIdx.x;  // 128
  int v = counts[t];
  s[t] = v;
  __syncthreads();
  for (int off = 1; off < N_GRAPHS; off <<= 1) {
    int a = (t >= off) ? s[t - off] : 0;
    __syncthreads();
    s[t] += a;
    __syncthreads();
  }
  gofs[t + 1] = s[t];
  if (t == 0) gofs[0] = 0;
}

// ---------------- split/swizzle prep ----------------
// Interleaved row layout: [hi Kg granules | lo Kg granules]; granule kb stored
// at physical slot kb ^ (row&7) within its section.

__global__ void k_prep_x(const float* __restrict__ x, ushort_t* __restrict__ xio) {
  int g = blockIdx.x * 256 + threadIdx.x;  // granule id
  if (g >= N_NODES * 8) return;
  int row = g >> 3, kb = g & 7;
  const float* p = x + (size_t)row * F_IN + kb * 8;
  us8 H, L;
#pragma unroll
  for (int i = 0; i < 8; ++i) {
    float f = p[i];
    unsigned short hi = f2bf(f);
    H[i] = hi;
    L[i] = f2bf(f - bf2f(hi));
  }
  size_t ob = (size_t)row * 128 + (size_t)((kb ^ (row & 7)) << 3);
  *(us8*)&xio[ob] = H;
  *(us8*)&xio[ob + 64] = L;
}

// all three layers' weights; W kept as separate hi/lo arrays (side-major).
__global__ void k_prep_w(const float* __restrict__ w1lp, const float* __restrict__ w1rp,
                         const float* __restrict__ w2lp, const float* __restrict__ w2rp,
                         const float* __restrict__ w3lp, const float* __restrict__ w3rp,
                         ushort_t* __restrict__ w1h, ushort_t* __restrict__ w1l,
                         ushort_t* __restrict__ w2h, ushort_t* __restrict__ w2l,
                         ushort_t* __restrict__ w3h, ushort_t* __restrict__ w3l) {
  int layer = blockIdx.z, side = blockIdx.y;
  const int Kg = (layer == 0) ? 8 : 32;
  int g = blockIdx.x * 256 + threadIdx.x;
  if (g >= 256 * Kg) return;
  const float* src = (layer == 0) ? (side ? w1rp : w1lp)
                   : (layer == 1) ? (side ? w2rp : w2lp)
                                  : (side ? w3rp : w3lp);
  ushort_t* dh = (layer == 0) ? w1h : (layer == 1) ? w2h : w3h;
  ushort_t* dl = (layer == 0) ? w1l : (layer == 1) ? w2l : w3l;
  int row = g / Kg, kb = g % Kg;
  const float* p = src + (size_t)row * (Kg * 8) + kb * 8;
  us8 H, L;
#pragma unroll
  for (int i = 0; i < 8; ++i) {
    float f = p[i];
    unsigned short hi = f2bf(f);
    H[i] = hi;
    L[i] = f2bf(f - bf2f(hi));
  }
  size_t ob = ((size_t)(side * 256 + row) * Kg + (kb ^ (row & 7))) * 8;
  *(us8*)&dh[ob] = H;
  *(us8*)&dl[ob] = L;
}

// ---------------- aggregation (gather over CSR) ----------------

__global__ __launch_bounds__(256) void k_agg64s(const float* __restrict__ x,
                                                const int* __restrict__ rowptr,
                                                const int* __restrict__ esrc,
                                                const float* __restrict__ deg_inv,
                                                ushort_t* __restrict__ oio) {
  int node = blockIdx.x * 4 + (threadIdx.x >> 6);
  if (node >= N_NODES) return;
  int lane = threadIdx.x & 63;
  int e0 = rowptr[node], e1 = rowptr[node + 1];
  float acc = 0.f;
  for (int e = e0; e < e1; ++e) acc += x[(size_t)esrc[e] * F_IN + lane];
  acc *= deg_inv[node];
  unsigned short hi = f2bf(acc);
  unsigned short lo = f2bf(acc - bf2f(hi));
  size_t rb = (size_t)node * 128;
  int slot = ((lane >> 3) ^ (node & 7)) << 3;
  oio[rb + slot + (lane & 7)] = hi;
  oio[rb + 64 + slot + (lane & 7)] = lo;
}

// one wave per node; single us8 load per edge covers the full 1KB hi|lo row.
__global__ __launch_bounds__(256) void k_agg256s(const ushort_t* __restrict__ hio,
                                                 const int* __restrict__ rowptr,
                                                 const int* __restrict__ esrc,
                                                 const float* __restrict__ deg_inv,
                                                 ushort_t* __restrict__ oio) {
  int node = blockIdx.x * 4 + (threadIdx.x >> 6);
  if (node >= N_NODES) return;
  int lane = threadIdx.x & 63;
  int gi = lane & 31;
  int sec = (lane >> 5) << 8;  // 0 = hi section, 256 = lo section (ushort offset)
  int e0 = rowptr[node], e1 = rowptr[node + 1];
  float a[8] = {0.f, 0.f, 0.f, 0.f, 0.f, 0.f, 0.f, 0.f};
  for (int e = e0; e < e1; ++e) {
    int s = esrc[e];
    us8 v = *(const us8*)&hio[(size_t)s * 512 + sec + ((gi ^ (s & 7)) << 3)];
#pragma unroll
    for (int i = 0; i < 8; ++i) a[i] += bf2f(v[i]);
  }
  float di = deg_inv[node];
  us8 H, L;
#pragma unroll
  for (int i = 0; i < 8; ++i) {
    float tot = (a[i] + __shfl_xor(a[i], 32)) * di;
    unsigned short hi = f2bf(tot);
    H[i] = hi;
    L[i] = f2bf(tot - bf2f(hi));
  }
  size_t rb = (size_t)node * 512 + (size_t)((gi ^ (node & 7)) << 3);
  if (lane < 32) *(us8*)&oio[rb] = H;
  else           *(us8*)&oio[rb + 256] = L;
}

// ---------------- split-bf16 MFMA GEMM ----------------
// out = relu(A1@W1^T + A2@W2^T + b). A interleaved [M_PAD][hi Kg | lo Kg] granules.
// W: [2*256, Kg] granules split hi/lo arrays. Tile 128x128, BK=64, 4 waves.

__global__ __launch_bounds__(256) void k_gemm_mfma(
    const ushort_t* __restrict__ A1, int k1g,
    const ushort_t* __restrict__ w1h, const ushort_t* __restrict__ w1l,
    const ushort_t* __restrict__ A2, int k2g,
    const ushort_t* __restrict__ w2h, const ushort_t* __restrict__ w2l,
    const float* __restrict__ bias, ushort_t* __restrict__ oio,
    float* __restrict__ ofp, int mode) {
  __shared__ __align__(16) ushort_t lds[4][8192];  // Ahi Alo Whi Wlo, 16KB each

  int t = threadIdx.x;
  int wv = t >> 6, lane = t & 63;
  int wr = wv >> 1, wc = wv & 1;
  int fr = lane & 15, kq = lane >> 4;
  int bm = blockIdx.x, bn = blockIdx.y;
  int rowA0 = bm * 128, rowW0 = bn * 128;

  f32x4 acc[4][4];
#pragma unroll
  for (int m = 0; m < 4; ++m)
#pragma unroll
    for (int n = 0; n < 4; ++n) acc[m][n] = (f32x4)0.f;

  const int ns1 = k1g >> 3, ns2 = k2g >> 3;
  const int lrow = wv * 32 + (lane >> 3);
  const int lj = lane & 7;

  for (int s = 0; s < ns1 + ns2; ++s) {
    const bool p2 = (s >= ns1);
    const ushort_t* A  = p2 ? A2 : A1;
    const ushort_t* Wh = p2 ? w2h : w1h;
    const ushort_t* Wl = p2 ? w2l : w1l;
    const int Kg = p2 ? k2g : k1g;
    const int ksg = (p2 ? (s - ns1) : s) * 8;

#pragma unroll
    for (int i = 0; i < 4; ++i) {
      int row = lrow + i * 8;
      size_t offA = ((size_t)(rowA0 + row) * (Kg * 2) + ksg + lj) * 8;
      size_t offW = ((size_t)(rowW0 + row) * Kg + ksg + lj) * 8;
      int lo = (wv * 256 + i * 64) * 8;
      gload16(A + offA, &lds[0][lo]);
      gload16(A + offA + (size_t)Kg * 8, &lds[1][lo]);
      gload16(Wh + offW, &lds[2][lo]);
      gload16(Wl + offW, &lds[3][lo]);
    }
    __syncthreads();  // drains vmcnt -> LDS tile ready

#pragma unroll
    for (int kc = 0; kc < 2; ++kc) {
      us8 ah[4], al[4], bh[4], bl[4];
      int kg = kc * 4 + kq;
      int swk = (kg ^ (fr & 7)) << 3;
#pragma unroll
      for (int m = 0; m < 4; ++m) {
        int off = ((wr * 64 + m * 16 + fr) << 6) + swk;
        ah[m] = *(const us8*)&lds[0][off];
        al[m] = *(const us8*)&lds[1][off];
      }
#pragma unroll
      for (int n = 0; n < 4; ++n) {
        int off = ((wc * 64 + n * 16 + fr) << 6) + swk;
        bh[n] = *(const us8*)&lds[2][off];
        bl[n] = *(const us8*)&lds[3][off];
      }
#pragma unroll
      for (int m = 0; m < 4; ++m)
#pragma unroll
        for (int n = 0; n < 4; ++n) {
          acc[m][n] = mfma_bf16(ah[m], bh[n], acc[m][n]);
          acc[m][n] = mfma_bf16(ah[m], bl[n], acc[m][n]);
          acc[m][n] = mfma_bf16(al[m], bh[n], acc[m][n]);
        }
    }
    __syncthreads();
  }

  // epilogue: C/D map col=lane&15, row=(lane>>4)*4+reg
#pragma unroll
  for (int n = 0; n < 4; ++n) {
    int colg = bn * 128 + wc * 64 + n * 16 + fr;
    float bv = bias[colg];
#pragma unroll
    for (int m = 0; m < 4; ++m) {
      f32x4 v = acc[m][n];
      int rowb = bm * 128 + wr * 64 + m * 16 + kq * 4;
#pragma unroll
      for (int r = 0; r < 4; ++r) {
        int rowg = rowb + r;
        if (rowg < N_NODES) {
          float h = fmaxf(v[r] + bv, 0.f);
          if (mode == 0) {
            unsigned short hi = f2bf(h);
            unsigned short lo = f2bf(h - bf2f(hi));
            int kbs = ((colg >> 3) ^ (rowg & 7)) << 3;
            size_t rb = (size_t)rowg * 512;
            oio[rb + kbs + (colg & 7)] = hi;
            oio[rb + 256 + kbs + (colg & 7)] = lo;
          } else {
            ofp[(size_t)rowg * HID + colg] = h;
          }
        }
      }
    }
  }
}

// ---------------- global mean pool (parallel over graph x chunk) ----------------

__global__ __launch_bounds__(256) void k_pool(const float* __restrict__ h,
                                              const int* __restrict__ gofs,
                                              float* __restrict__ pooled) {
  int g = blockIdx.y, c = blockIdx.x;  // 16 chunks
  int r0 = gofs[g], r1 = gofs[g + 1];
  int rg = threadIdx.x >> 6, lane = threadIdx.x & 63;
  float ax = 0.f, ay = 0.f, az = 0.f, aw = 0.f;
  for (int r = r0 + c * 4 + rg; r < r1; r += 64) {
    float4 v = *(const float4*)&h[(size_t)r * HID + lane * 4];
    ax += v.x; ay += v.y; az += v.z; aw += v.w;
  }
  __shared__ float4 sm[4][64];
  sm[rg][lane] = make_float4(ax, ay, az, aw);
  __syncthreads();
  if (rg == 0) {
    float4 s0 = sm[0][lane], s1 = sm[1][lane], s2 = sm[2][lane], s3 = sm[3][lane];
    float* p = &pooled[g * HID + lane * 4];
    atomicAdd(p + 0, s0.x + s1.x + s2.x + s3.x);
    atomicAdd(p + 1, s0.y + s1.y + s2.y + s3.y);
    atomicAdd(p + 2, s0.z + s1.z + s2.z + s3.z);
    atomicAdd(p + 3, s0.w + s1.w + s2.w + s3.w);
  }
}

// ---------------- head ----------------

__global__ __launch_bounds__(128) void k_head(const float* __restrict__ pooled,
                                              const int* __restrict__ counts,
                                              const float* __restrict__ w1,
                                              const float* __restrict__ b1,
                                              const float* __restrict__ w2,
                                              const float* __restrict__ b2,
                                              float* __restrict__ out) {
  __shared__ float p[HID];
  __shared__ float g1[HID / 2];
  int g = blockIdx.x, t = threadIdx.x;
  float inv = 1.f / fmaxf((float)counts[g], 1.f);
  p[t] = pooled[g * HID + t] * inv;
  p[t + 128] = pooled[g * HID + 128 + t] * inv;
  __syncthreads();
  float s = b1[t];
#pragma unroll 4
  for (int k = 0; k < HID; ++k) s = fmaf(p[k], w1[t * HID + k], s);
  g1[t] = fmaxf(s, 0.f);
  __syncthreads();
  if (t < N_OUT) {
    float s2 = b2[t];
#pragma unroll 4
    for (int k = 0; k < HID / 2; ++k) s2 = fmaf(g1[k], w2[t * (HID / 2) + k], s2);
    out[g * N_OUT + t] = s2;
  }
}

// ---------------- launch ----------------

extern "C" void kernel_launch(void* const* d_in, const int* in_sizes, int n_in,
                              void* d_out, int out_size, void* d_ws, size_t ws_size,
                              hipStream_t stream) {
  const float* x      = (const float*)d_in[0];
  const int*   ei     = (const int*)d_in[1];
  const int*   batch  = (const int*)d_in[2];
  const float* w1lw   = (const float*)d_in[3];
  const float* b1     = (const float*)d_in[4];
  const float* w1rw   = (const float*)d_in[5];
  const float* w2lw   = (const float*)d_in[6];
  const float* b2     = (const float*)d_in[7];
  const float* w2rw   = (const float*)d_in[8];
  const float* w3lw   = (const float*)d_in[9];
  const float* b3     = (const float*)d_in[10];
  const float* w3rw   = (const float*)d_in[11];
  const float* lin1_w = (const float*)d_in[12];
  const float* lin1_b = (const float*)d_in[13];
  const float* lin2_w = (const float*)d_in[14];
  const float* lin2_b = (const float*)d_in[15];
  float* out = (float*)d_out;

  const int* srcIdx = ei;
  const int* dstIdx = ei + N_EDGES;

  size_t off = 0;
  auto carve = [&](size_t bytes) {
    size_t r = off;
    off += (bytes + 255) & ~(size_t)255;
    return r;
  };
  char* ws = (char*)d_ws;
  int*      deg     = (int*)(ws + carve((size_t)N_NODES * 4));
  int*      rowptr  = (int*)(ws + carve((size_t)(N_NODES + 1) * 4));
  int*      cursor  = (int*)(ws + carve((size_t)N_NODES * 4));
  float*    deg_inv = (float*)(ws + carve((size_t)N_NODES * 4));
  int*      esrc    = (int*)(ws + carve((size_t)N_EDGES * 4));
  int*      partial = (int*)(ws + carve(64 * 4));
  int*      gofs    = (int*)(ws + carve((N_GRAPHS + 1) * 4));
  ushort_t* xio     = (ushort_t*)(ws + carve((size_t)M_PAD * 128 * 2));
  ushort_t* agg     = (ushort_t*)(ws + carve((size_t)M_PAD * 512 * 2));
  char*     h1blk   = ws + carve((size_t)M_PAD * 512 * 2);  // h1 bf16-pair OR h3 fp32
  ushort_t* h1      = (ushort_t*)h1blk;
  float*    h3      = (float*)h1blk;  // alias: h1 dead before gemm3 writes
  ushort_t* h2      = (ushort_t*)(ws + carve((size_t)M_PAD * 512 * 2));
  ushort_t* w1hi    = (ushort_t*)(ws + carve((size_t)2 * 256 * F_IN * 2));
  ushort_t* w1lo    = (ushort_t*)(ws + carve((size_t)2 * 256 * F_IN * 2));
  ushort_t* w2hi    = (ushort_t*)(ws + carve((size_t)2 * 256 * HID * 2));
  ushort_t* w2lo    = (ushort_t*)(ws + carve((size_t)2 * 256 * HID * 2));
  ushort_t* w3hi    = (ushort_t*)(ws + carve((size_t)2 * 256 * HID * 2));
  ushort_t* w3lo    = (ushort_t*)(ws + carve((size_t)2 * 256 * HID * 2));
  float*    pooled  = (float*)(ws + carve((size_t)N_GRAPHS * HID * 4));
  int*      counts  = (int*)(ws + carve((size_t)N_GRAPHS * 4));
  (void)ws_size; (void)n_in; (void)in_sizes; (void)out_size;

  hipMemsetAsync(deg, 0, (size_t)N_NODES * 4, stream);
  hipMemsetAsync(counts, 0, (size_t)N_GRAPHS * 4, stream);
  hipMemsetAsync(pooled, 0, (size_t)N_GRAPHS * HID * 4, stream);

  const int EB = (N_EDGES + 255) / 256;
  const int SB = (N_NODES + 1023) / 1024;

  k_hist<<<EB, 256, 0, stream>>>(dstIdx, batch, deg, counts);
  k_scan1<<<SB, 1024, 0, stream>>>(deg, rowptr, partial);
  k_scan2<<<1, 64, 0, stream>>>(partial, rowptr);
  k_scan3<<<SB, 1024, 0, stream>>>(deg, partial, rowptr, cursor, deg_inv);
  k_scatter<<<EB, 256, 0, stream>>>(srcIdx, dstIdx, cursor, esrc);
  k_gofs<<<1, N_GRAPHS, 0, stream>>>(counts, gofs);

  k_prep_x<<<(N_NODES * 8 + 255) / 256, 256, 0, stream>>>(x, xio);
  k_prep_w<<<dim3(32, 2, 3), 256, 0, stream>>>(w1lw, w1rw, w2lw, w2rw, w3lw, w3rw,
                                               w1hi, w1lo, w2hi, w2lo, w3hi, w3lo);

  dim3 ggrid((N_NODES + 127) / 128, 2);
  const int AB = N_NODES / 4;

  // layer 1
  k_agg64s<<<AB, 256, 0, stream>>>(x, rowptr, esrc, deg_inv, agg);
  k_gemm_mfma<<<ggrid, 256, 0, stream>>>(agg, 8, w1hi, w1lo,
                                         xio, 8, w1hi + 256 * F_IN, w1lo + 256 * F_IN,
                                         b1, h1, nullptr, 0);
  // layer 2
  k_agg256s<<<AB, 256, 0, stream>>>(h1, rowptr, esrc, deg_inv, agg);
  k_gemm_mfma<<<ggrid, 256, 0, stream>>>(agg, 32, w2hi, w2lo,
                                         h1, 32, w2hi + 256 * HID, w2lo + 256 * HID,
                                         b2, h2, nullptr, 0);
  // layer 3 (fp32 out for pooling; h3 aliases dead h1)
  k_agg256s<<<AB, 256, 0, stream>>>(h2, rowptr, esrc, deg_inv, agg);
  k_gemm_mfma<<<ggrid, 256, 0, stream>>>(agg, 32, w3hi, w3lo,
                                         h2, 32, w3hi + 256 * HID, w3lo + 256 * HID,
                                         b3, nullptr, h3, 1);

  k_pool<<<dim3(16, N_GRAPHS), 256, 0, stream>>>(h3, gofs, pooled);
  k_head<<<N_GRAPHS, 128, 0, stream>>>(pooled, gofs /*unused*/ == nullptr ? nullptr : counts,
                                       lin1_w, lin1_b, lin2_w, lin2_b, out);
}

// Round 4
// 595.361 us; speedup vs baseline: 2.0197x; 1.2637x over previous
//
#include <hip/hip_runtime.h>

#define N_NODES 50000
#define M_PAD   50048   // padded rows so global_load_lds never reads past buffers
#define N_EDGES 800000
#define F_IN 64
#define HID 256
#define N_GRAPHS 128
#define N_OUT 24

typedef unsigned short ushort_t;
typedef __attribute__((ext_vector_type(8))) unsigned short us8;
typedef __attribute__((ext_vector_type(8))) __bf16 bf16x8;
typedef __attribute__((ext_vector_type(4))) float f32x4;

__device__ __forceinline__ unsigned short f2bf(float f) {
  unsigned u = __builtin_bit_cast(unsigned, f);
  return (unsigned short)((u + 0x7fffu + ((u >> 16) & 1u)) >> 16);
}
__device__ __forceinline__ float bf2f(unsigned short h) {
  return __builtin_bit_cast(float, (unsigned)h << 16);
}

__device__ __forceinline__ f32x4 mfma_bf16(us8 a, us8 b, f32x4 c) {
  return __builtin_amdgcn_mfma_f32_16x16x32_bf16(
      __builtin_bit_cast(bf16x8, a), __builtin_bit_cast(bf16x8, b), c, 0, 0, 0);
}

__device__ __forceinline__ void gload16(const ushort_t* g, ushort_t* l) {
  __builtin_amdgcn_global_load_lds(
      (const __attribute__((address_space(1))) void*)g,
      (__attribute__((address_space(3))) void*)l, 16, 0, 0);
}

// ---------------- CSR build (privatized histogram, atomic-free scatter) ----------------

// 8-way privatized degree histogram; records each edge's rank within (copy,dst).
__global__ void k_hist(const int* __restrict__ dst, int* __restrict__ deg_priv,
                       int* __restrict__ rank) {
  int e = blockIdx.x * 256 + threadIdx.x;
  if (e < N_EDGES) {
    int c = blockIdx.x & 7;
    rank[e] = atomicAdd(&deg_priv[c * N_NODES + dst[e]], 1);
  }
}

// batch is sorted: gofs[g] = first index with batch[i] >= g (binary search, no atomics).
__global__ void k_gofs(const int* __restrict__ batch, int* __restrict__ gofs) {
  int t = threadIdx.x;
  if (t > N_GRAPHS) return;
  int lo = 0, hi = N_NODES;
  while (lo < hi) {
    int mid = (lo + hi) >> 1;
    if (batch[mid] < t) lo = mid + 1;
    else hi = mid;
  }
  gofs[t] = lo;
}

// fused: reduce 8 copies -> per-copy exclusive offsets (in place) + total deg,
// then block-local exclusive scan of deg.
__global__ __launch_bounds__(1024) void k_scan1(int* __restrict__ deg_priv,
                                                int* __restrict__ deg,
                                                int* __restrict__ rowptr,
                                                int* __restrict__ partial) {
  __shared__ int s[1024];
  int t = threadIdx.x;
  int idx = blockIdx.x * 1024 + t;
  int v = 0;
  if (idx < N_NODES) {
    int run = 0;
#pragma unroll
    for (int c = 0; c < 8; ++c) {
      int dv = deg_priv[c * N_NODES + idx];
      deg_priv[c * N_NODES + idx] = run;  // exclusive offset among copies
      run += dv;
    }
    deg[idx] = run;
    v = run;
  }
  s[t] = v;
  __syncthreads();
  for (int off = 1; off < 1024; off <<= 1) {
    int a = (t >= off) ? s[t - off] : 0;
    __syncthreads();
    s[t] += a;
    __syncthreads();
  }
  if (idx < N_NODES) rowptr[idx] = s[t] - v;  // local exclusive
  if (t == 1023) partial[blockIdx.x] = s[1023];
}

__global__ void k_scan2(int* __restrict__ partial, int* __restrict__ rowptr) {
  __shared__ int s[64];
  int t = threadIdx.x;  // 64 threads, 1 block
  const int NB = (N_NODES + 1023) / 1024;
  int v = (t < NB) ? partial[t] : 0;
  s[t] = v;
  __syncthreads();
  for (int off = 1; off < 64; off <<= 1) {
    int a = (t >= off) ? s[t - off] : 0;
    __syncthreads();
    s[t] += a;
    __syncthreads();
  }
  if (t < NB) partial[t] = s[t] - v;  // exclusive block offsets
  if (t == NB - 1) rowptr[N_NODES] = s[t];
}

__global__ __launch_bounds__(1024) void k_scan3(const int* __restrict__ deg,
                                                const int* __restrict__ partial,
                                                int* __restrict__ rowptr,
                                                float* __restrict__ deg_inv) {
  int idx = blockIdx.x * 1024 + threadIdx.x;
  if (idx < N_NODES) {
    rowptr[idx] += partial[blockIdx.x];
    deg_inv[idx] = 1.0f / fmaxf((float)deg[idx], 1.0f);
  }
}

// atomic-free placement: slot = rowptr[d] + copyoff[c][d] + rank[e].
// Must use the SAME blockIdx->copy mapping as k_hist.
__global__ void k_place(const int* __restrict__ src, const int* __restrict__ dst,
                        const int* __restrict__ rowptr, const int* __restrict__ deg_priv,
                        const int* __restrict__ rank, int* __restrict__ esrc) {
  int e = blockIdx.x * 256 + threadIdx.x;
  if (e < N_EDGES) {
    int c = blockIdx.x & 7;
    int d = dst[e];
    esrc[rowptr[d] + deg_priv[c * N_NODES + d] + rank[e]] = src[e];
  }
}

// ---------------- split/swizzle prep ----------------
// Interleaved row layout: [hi Kg granules | lo Kg granules]; granule kb stored
// at physical slot kb ^ (row&7) within its section.

__global__ void k_prep_x(const float* __restrict__ x, ushort_t* __restrict__ xio) {
  int g = blockIdx.x * 256 + threadIdx.x;  // granule id
  if (g >= N_NODES * 8) return;
  int row = g >> 3, kb = g & 7;
  const float* p = x + (size_t)row * F_IN + kb * 8;
  us8 H, L;
#pragma unroll
  for (int i = 0; i < 8; ++i) {
    float f = p[i];
    unsigned short hi = f2bf(f);
    H[i] = hi;
    L[i] = f2bf(f - bf2f(hi));
  }
  size_t ob = (size_t)row * 128 + (size_t)((kb ^ (row & 7)) << 3);
  *(us8*)&xio[ob] = H;
  *(us8*)&xio[ob + 64] = L;
}

// all three layers' weights; W kept as separate hi/lo arrays (side-major).
__global__ void k_prep_w(const float* __restrict__ w1lp, const float* __restrict__ w1rp,
                         const float* __restrict__ w2lp, const float* __restrict__ w2rp,
                         const float* __restrict__ w3lp, const float* __restrict__ w3rp,
                         ushort_t* __restrict__ w1h, ushort_t* __restrict__ w1l,
                         ushort_t* __restrict__ w2h, ushort_t* __restrict__ w2l,
                         ushort_t* __restrict__ w3h, ushort_t* __restrict__ w3l) {
  int layer = blockIdx.z, side = blockIdx.y;
  const int Kg = (layer == 0) ? 8 : 32;
  int g = blockIdx.x * 256 + threadIdx.x;
  if (g >= 256 * Kg) return;
  const float* src = (layer == 0) ? (side ? w1rp : w1lp)
                   : (layer == 1) ? (side ? w2rp : w2lp)
                                  : (side ? w3rp : w3lp);
  ushort_t* dh = (layer == 0) ? w1h : (layer == 1) ? w2h : w3h;
  ushort_t* dl = (layer == 0) ? w1l : (layer == 1) ? w2l : w3l;
  int row = g / Kg, kb = g % Kg;
  const float* p = src + (size_t)row * (Kg * 8) + kb * 8;
  us8 H, L;
#pragma unroll
  for (int i = 0; i < 8; ++i) {
    float f = p[i];
    unsigned short hi = f2bf(f);
    H[i] = hi;
    L[i] = f2bf(f - bf2f(hi));
  }
  size_t ob = ((size_t)(side * 256 + row) * Kg + (kb ^ (row & 7))) * 8;
  *(us8*)&dh[ob] = H;
  *(us8*)&dl[ob] = L;
}

// ---------------- aggregation (gather over CSR) ----------------

__global__ __launch_bounds__(256) void k_agg64s(const float* __restrict__ x,
                                                const int* __restrict__ rowptr,
                                                const int* __restrict__ esrc,
                                                const float* __restrict__ deg_inv,
                                                ushort_t* __restrict__ oio) {
  int node = blockIdx.x * 4 + (threadIdx.x >> 6);
  if (node >= N_NODES) return;
  int lane = threadIdx.x & 63;
  int e0 = rowptr[node], e1 = rowptr[node + 1];
  float acc = 0.f;
  for (int e = e0; e < e1; ++e) acc += x[(size_t)esrc[e] * F_IN + lane];
  acc *= deg_inv[node];
  unsigned short hi = f2bf(acc);
  unsigned short lo = f2bf(acc - bf2f(hi));
  size_t rb = (size_t)node * 128;
  int slot = ((lane >> 3) ^ (node & 7)) << 3;
  oio[rb + slot + (lane & 7)] = hi;
  oio[rb + 64 + slot + (lane & 7)] = lo;
}

// one wave per node; single us8 load per edge covers the full 1KB hi|lo row.
__global__ __launch_bounds__(256) void k_agg256s(const ushort_t* __restrict__ hio,
                                                 const int* __restrict__ rowptr,
                                                 const int* __restrict__ esrc,
                                                 const float* __restrict__ deg_inv,
                                                 ushort_t* __restrict__ oio) {
  int node = blockIdx.x * 4 + (threadIdx.x >> 6);
  if (node >= N_NODES) return;
  int lane = threadIdx.x & 63;
  int gi = lane & 31;
  int sec = (lane >> 5) << 8;  // 0 = hi section, 256 = lo section (ushort offset)
  int e0 = rowptr[node], e1 = rowptr[node + 1];
  float a[8] = {0.f, 0.f, 0.f, 0.f, 0.f, 0.f, 0.f, 0.f};
  for (int e = e0; e < e1; ++e) {
    int s = esrc[e];
    us8 v = *(const us8*)&hio[(size_t)s * 512 + sec + ((gi ^ (s & 7)) << 3)];
#pragma unroll
    for (int i = 0; i < 8; ++i) a[i] += bf2f(v[i]);
  }
  float di = deg_inv[node];
  us8 H, L;
#pragma unroll
  for (int i = 0; i < 8; ++i) {
    float tot = (a[i] + __shfl_xor(a[i], 32)) * di;
    unsigned short hi = f2bf(tot);
    H[i] = hi;
    L[i] = f2bf(tot - bf2f(hi));
  }
  size_t rb = (size_t)node * 512 + (size_t)((gi ^ (node & 7)) << 3);
  if (lane < 32) *(us8*)&oio[rb] = H;
  else           *(us8*)&oio[rb + 256] = L;
}

// ---------------- split-bf16 MFMA GEMM ----------------
// out = relu(A1@W1^T + A2@W2^T + b). A interleaved [M_PAD][hi Kg | lo Kg] granules.
// W: [2*256, Kg] granules split hi/lo arrays. Tile 128x128, BK=64, 4 waves.

__global__ __launch_bounds__(256) void k_gemm_mfma(
    const ushort_t* __restrict__ A1, int k1g,
    const ushort_t* __restrict__ w1h, const ushort_t* __restrict__ w1l,
    const ushort_t* __restrict__ A2, int k2g,
    const ushort_t* __restrict__ w2h, const ushort_t* __restrict__ w2l,
    const float* __restrict__ bias, ushort_t* __restrict__ oio,
    float* __restrict__ ofp, int mode) {
  __shared__ __align__(16) ushort_t lds[4][8192];  // Ahi Alo Whi Wlo, 16KB each

  int t = threadIdx.x;
  int wv = t >> 6, lane = t & 63;
  int wr = wv >> 1, wc = wv & 1;
  int fr = lane & 15, kq = lane >> 4;
  int bm = blockIdx.x, bn = blockIdx.y;
  int rowA0 = bm * 128, rowW0 = bn * 128;

  f32x4 acc[4][4];
#pragma unroll
  for (int m = 0; m < 4; ++m)
#pragma unroll
    for (int n = 0; n < 4; ++n) acc[m][n] = (f32x4)0.f;

  const int ns1 = k1g >> 3, ns2 = k2g >> 3;
  const int lrow = wv * 32 + (lane >> 3);
  const int lj = lane & 7;

  for (int s = 0; s < ns1 + ns2; ++s) {
    const bool p2 = (s >= ns1);
    const ushort_t* A  = p2 ? A2 : A1;
    const ushort_t* Wh = p2 ? w2h : w1h;
    const ushort_t* Wl = p2 ? w2l : w1l;
    const int Kg = p2 ? k2g : k1g;
    const int ksg = (p2 ? (s - ns1) : s) * 8;

#pragma unroll
    for (int i = 0; i < 4; ++i) {
      int row = lrow + i * 8;
      size_t offA = ((size_t)(rowA0 + row) * (Kg * 2) + ksg + lj) * 8;
      size_t offW = ((size_t)(rowW0 + row) * Kg + ksg + lj) * 8;
      int lo = (wv * 256 + i * 64) * 8;
      gload16(A + offA, &lds[0][lo]);
      gload16(A + offA + (size_t)Kg * 8, &lds[1][lo]);
      gload16(Wh + offW, &lds[2][lo]);
      gload16(Wl + offW, &lds[3][lo]);
    }
    __syncthreads();  // drains vmcnt -> LDS tile ready

#pragma unroll
    for (int kc = 0; kc < 2; ++kc) {
      us8 ah[4], al[4], bh[4], bl[4];
      int kg = kc * 4 + kq;
      int swk = (kg ^ (fr & 7)) << 3;
#pragma unroll
      for (int m = 0; m < 4; ++m) {
        int off = ((wr * 64 + m * 16 + fr) << 6) + swk;
        ah[m] = *(const us8*)&lds[0][off];
        al[m] = *(const us8*)&lds[1][off];
      }
#pragma unroll
      for (int n = 0; n < 4; ++n) {
        int off = ((wc * 64 + n * 16 + fr) << 6) + swk;
        bh[n] = *(const us8*)&lds[2][off];
        bl[n] = *(const us8*)&lds[3][off];
      }
#pragma unroll
      for (int m = 0; m < 4; ++m)
#pragma unroll
        for (int n = 0; n < 4; ++n) {
          acc[m][n] = mfma_bf16(ah[m], bh[n], acc[m][n]);
          acc[m][n] = mfma_bf16(ah[m], bl[n], acc[m][n]);
          acc[m][n] = mfma_bf16(al[m], bh[n], acc[m][n]);
        }
    }
    __syncthreads();
  }

  // epilogue: C/D map col=lane&15, row=(lane>>4)*4+reg
#pragma unroll
  for (int n = 0; n < 4; ++n) {
    int colg = bn * 128 + wc * 64 + n * 16 + fr;
    float bv = bias[colg];
#pragma unroll
    for (int m = 0; m < 4; ++m) {
      f32x4 v = acc[m][n];
      int rowb = bm * 128 + wr * 64 + m * 16 + kq * 4;
#pragma unroll
      for (int r = 0; r < 4; ++r) {
        int rowg = rowb + r;
        if (rowg < N_NODES) {
          float h = fmaxf(v[r] + bv, 0.f);
          if (mode == 0) {
            unsigned short hi = f2bf(h);
            unsigned short lo = f2bf(h - bf2f(hi));
            int kbs = ((colg >> 3) ^ (rowg & 7)) << 3;
            size_t rb = (size_t)rowg * 512;
            oio[rb + kbs + (colg & 7)] = hi;
            oio[rb + 256 + kbs + (colg & 7)] = lo;
          } else {
            ofp[(size_t)rowg * HID + colg] = h;
          }
        }
      }
    }
  }
}

// ---------------- global mean pool (parallel over graph x chunk) ----------------

__global__ __launch_bounds__(256) void k_pool(const float* __restrict__ h,
                                              const int* __restrict__ gofs,
                                              float* __restrict__ pooled) {
  int g = blockIdx.y, c = blockIdx.x;  // 16 chunks
  int r0 = gofs[g], r1 = gofs[g + 1];
  int rg = threadIdx.x >> 6, lane = threadIdx.x & 63;
  float ax = 0.f, ay = 0.f, az = 0.f, aw = 0.f;
  for (int r = r0 + c * 4 + rg; r < r1; r += 64) {
    float4 v = *(const float4*)&h[(size_t)r * HID + lane * 4];
    ax += v.x; ay += v.y; az += v.z; aw += v.w;
  }
  __shared__ float4 sm[4][64];
  sm[rg][lane] = make_float4(ax, ay, az, aw);
  __syncthreads();
  if (rg == 0) {
    float4 s0 = sm[0][lane], s1 = sm[1][lane], s2 = sm[2][lane], s3 = sm[3][lane];
    float* p = &pooled[g * HID + lane * 4];
    atomicAdd(p + 0, s0.x + s1.x + s2.x + s3.x);
    atomicAdd(p + 1, s0.y + s1.y + s2.y + s3.y);
    atomicAdd(p + 2, s0.z + s1.z + s2.z + s3.z);
    atomicAdd(p + 3, s0.w + s1.w + s2.w + s3.w);
  }
}

// ---------------- head ----------------

__global__ __launch_bounds__(128) void k_head(const float* __restrict__ pooled,
                                              const int* __restrict__ gofs,
                                              const float* __restrict__ w1,
                                              const float* __restrict__ b1,
                                              const float* __restrict__ w2,
                                              const float* __restrict__ b2,
                                              float* __restrict__ out) {
  __shared__ float p[HID];
  __shared__ float g1[HID / 2];
  int g = blockIdx.x, t = threadIdx.x;
  float inv = 1.f / fmaxf((float)(gofs[g + 1] - gofs[g]), 1.f);
  p[t] = pooled[g * HID + t] * inv;
  p[t + 128] = pooled[g * HID + 128 + t] * inv;
  __syncthreads();
  float s = b1[t];
#pragma unroll 4
  for (int k = 0; k < HID; ++k) s = fmaf(p[k], w1[t * HID + k], s);
  g1[t] = fmaxf(s, 0.f);
  __syncthreads();
  if (t < N_OUT) {
    float s2 = b2[t];
#pragma unroll 4
    for (int k = 0; k < HID / 2; ++k) s2 = fmaf(g1[k], w2[t * (HID / 2) + k], s2);
    out[g * N_OUT + t] = s2;
  }
}

// ---------------- launch ----------------

extern "C" void kernel_launch(void* const* d_in, const int* in_sizes, int n_in,
                              void* d_out, int out_size, void* d_ws, size_t ws_size,
                              hipStream_t stream) {
  const float* x      = (const float*)d_in[0];
  const int*   ei     = (const int*)d_in[1];
  const int*   batch  = (const int*)d_in[2];
  const float* w1lw   = (const float*)d_in[3];
  const float* b1     = (const float*)d_in[4];
  const float* w1rw   = (const float*)d_in[5];
  const float* w2lw   = (const float*)d_in[6];
  const float* b2     = (const float*)d_in[7];
  const float* w2rw   = (const float*)d_in[8];
  const float* w3lw   = (const float*)d_in[9];
  const float* b3     = (const float*)d_in[10];
  const float* w3rw   = (const float*)d_in[11];
  const float* lin1_w = (const float*)d_in[12];
  const float* lin1_b = (const float*)d_in[13];
  const float* lin2_w = (const float*)d_in[14];
  const float* lin2_b = (const float*)d_in[15];
  float* out = (float*)d_out;

  const int* srcIdx = ei;
  const int* dstIdx = ei + N_EDGES;

  size_t off = 0;
  auto carve = [&](size_t bytes) {
    size_t r = off;
    off += (bytes + 255) & ~(size_t)255;
    return r;
  };
  char* ws = (char*)d_ws;
  int*      deg_priv = (int*)(ws + carve((size_t)8 * N_NODES * 4));
  int*      deg      = (int*)(ws + carve((size_t)N_NODES * 4));
  int*      rank     = (int*)(ws + carve((size_t)N_EDGES * 4));
  int*      rowptr   = (int*)(ws + carve((size_t)(N_NODES + 1) * 4));
  float*    deg_inv  = (float*)(ws + carve((size_t)N_NODES * 4));
  int*      esrc     = (int*)(ws + carve((size_t)N_EDGES * 4));
  int*      partial  = (int*)(ws + carve(64 * 4));
  int*      gofs     = (int*)(ws + carve((N_GRAPHS + 1) * 4));
  ushort_t* xio      = (ushort_t*)(ws + carve((size_t)M_PAD * 128 * 2));
  ushort_t* agg      = (ushort_t*)(ws + carve((size_t)M_PAD * 512 * 2));
  char*     h1blk    = ws + carve((size_t)M_PAD * 512 * 2);  // h1 bf16-pair OR h3 fp32
  ushort_t* h1       = (ushort_t*)h1blk;
  float*    h3       = (float*)h1blk;  // alias: h1 dead before gemm3 writes
  ushort_t* h2       = (ushort_t*)(ws + carve((size_t)M_PAD * 512 * 2));
  ushort_t* w1hi     = (ushort_t*)(ws + carve((size_t)2 * 256 * F_IN * 2));
  ushort_t* w1lo     = (ushort_t*)(ws + carve((size_t)2 * 256 * F_IN * 2));
  ushort_t* w2hi     = (ushort_t*)(ws + carve((size_t)2 * 256 * HID * 2));
  ushort_t* w2lo     = (ushort_t*)(ws + carve((size_t)2 * 256 * HID * 2));
  ushort_t* w3hi     = (ushort_t*)(ws + carve((size_t)2 * 256 * HID * 2));
  ushort_t* w3lo     = (ushort_t*)(ws + carve((size_t)2 * 256 * HID * 2));
  float*    pooled   = (float*)(ws + carve((size_t)N_GRAPHS * HID * 4));
  (void)ws_size; (void)n_in; (void)in_sizes; (void)out_size;

  hipMemsetAsync(deg_priv, 0, (size_t)8 * N_NODES * 4, stream);
  hipMemsetAsync(pooled, 0, (size_t)N_GRAPHS * HID * 4, stream);

  const int EB = (N_EDGES + 255) / 256;
  const int SB = (N_NODES + 1023) / 1024;

  k_hist<<<EB, 256, 0, stream>>>(dstIdx, deg_priv, rank);
  k_gofs<<<1, 256, 0, stream>>>(batch, gofs);
  k_scan1<<<SB, 1024, 0, stream>>>(deg_priv, deg, rowptr, partial);
  k_scan2<<<1, 64, 0, stream>>>(partial, rowptr);
  k_scan3<<<SB, 1024, 0, stream>>>(deg, partial, rowptr, deg_inv);
  k_place<<<EB, 256, 0, stream>>>(srcIdx, dstIdx, rowptr, deg_priv, rank, esrc);

  k_prep_x<<<(N_NODES * 8 + 255) / 256, 256, 0, stream>>>(x, xio);
  k_prep_w<<<dim3(32, 2, 3), 256, 0, stream>>>(w1lw, w1rw, w2lw, w2rw, w3lw, w3rw,
                                               w1hi, w1lo, w2hi, w2lo, w3hi, w3lo);

  dim3 ggrid((N_NODES + 127) / 128, 2);
  const int AB = N_NODES / 4;

  // layer 1
  k_agg64s<<<AB, 256, 0, stream>>>(x, rowptr, esrc, deg_inv, agg);
  k_gemm_mfma<<<ggrid, 256, 0, stream>>>(agg, 8, w1hi, w1lo,
                                         xio, 8, w1hi + 256 * F_IN, w1lo + 256 * F_IN,
                                         b1, h1, nullptr, 0);
  // layer 2
  k_agg256s<<<AB, 256, 0, stream>>>(h1, rowptr, esrc, deg_inv, agg);
  k_gemm_mfma<<<ggrid, 256, 0, stream>>>(agg, 32, w2hi, w2lo,
                                         h1, 32, w2hi + 256 * HID, w2lo + 256 * HID,
                                         b2, h2, nullptr, 0);
  // layer 3 (fp32 out for pooling; h3 aliases dead h1)
  k_agg256s<<<AB, 256, 0, stream>>>(h2, rowptr, esrc, deg_inv, agg);
  k_gemm_mfma<<<ggrid, 256, 0, stream>>>(agg, 32, w3hi, w3lo,
                                         h2, 32, w3hi + 256 * HID, w3lo + 256 * HID,
                                         b3, nullptr, h3, 1);

  k_pool<<<dim3(16, N_GRAPHS), 256, 0, stream>>>(h3, gofs, pooled);
  k_head<<<N_GRAPHS, 128, 0, stream>>>(pooled, gofs, lin1_w, lin1_b, lin2_w, lin2_b, out);
}

// Round 5
// 551.357 us; speedup vs baseline: 2.1809x; 1.0798x over previous
//
#include <hip/hip_runtime.h>

#define N_NODES 50000
#define M_PAD   50048   // padded rows so global_load_lds never reads past buffers
#define N_EDGES 800000
#define F_IN 64
#define HID 256
#define N_GRAPHS 128
#define N_OUT 24

typedef unsigned short ushort_t;
typedef __attribute__((ext_vector_type(8))) unsigned short us8;
typedef __attribute__((ext_vector_type(8))) __bf16 bf16x8;
typedef __attribute__((ext_vector_type(4))) float f32x4;

__device__ __forceinline__ unsigned short f2bf(float f) {
  unsigned u = __builtin_bit_cast(unsigned, f);
  return (unsigned short)((u + 0x7fffu + ((u >> 16) & 1u)) >> 16);
}
__device__ __forceinline__ float bf2f(unsigned short h) {
  return __builtin_bit_cast(float, (unsigned)h << 16);
}

__device__ __forceinline__ f32x4 mfma_bf16(us8 a, us8 b, f32x4 c) {
  return __builtin_amdgcn_mfma_f32_16x16x32_bf16(
      __builtin_bit_cast(bf16x8, a), __builtin_bit_cast(bf16x8, b), c, 0, 0, 0);
}

__device__ __forceinline__ void gload16(const ushort_t* g, ushort_t* l) {
  __builtin_amdgcn_global_load_lds(
      (const __attribute__((address_space(1))) void*)g,
      (__attribute__((address_space(3))) void*)l, 16, 0, 0);
}

// ---------------- CSR build (privatized histogram, atomic-free scatter) ----------------

// 8-way privatized degree histogram; records each edge's rank within (copy,dst).
__global__ void k_hist(const int* __restrict__ dst, int* __restrict__ deg_priv,
                       int* __restrict__ rank) {
  int e = blockIdx.x * 256 + threadIdx.x;
  if (e < N_EDGES) {
    int c = blockIdx.x & 7;
    rank[e] = atomicAdd(&deg_priv[c * N_NODES + dst[e]], 1);
  }
}

// batch is sorted: gofs[g] = first index with batch[i] >= g (binary search, no atomics).
__global__ void k_gofs(const int* __restrict__ batch, int* __restrict__ gofs) {
  int t = threadIdx.x;
  if (t > N_GRAPHS) return;
  int lo = 0, hi = N_NODES;
  while (lo < hi) {
    int mid = (lo + hi) >> 1;
    if (batch[mid] < t) lo = mid + 1;
    else hi = mid;
  }
  gofs[t] = lo;
}

// fused: reduce 8 copies -> per-copy exclusive offsets (in place) + total deg,
// then block-local exclusive scan of deg.
__global__ __launch_bounds__(1024) void k_scan1(int* __restrict__ deg_priv,
                                                int* __restrict__ deg,
                                                int* __restrict__ rowptr,
                                                int* __restrict__ partial) {
  __shared__ int s[1024];
  int t = threadIdx.x;
  int idx = blockIdx.x * 1024 + t;
  int v = 0;
  if (idx < N_NODES) {
    int run = 0;
#pragma unroll
    for (int c = 0; c < 8; ++c) {
      int dv = deg_priv[c * N_NODES + idx];
      deg_priv[c * N_NODES + idx] = run;  // exclusive offset among copies
      run += dv;
    }
    deg[idx] = run;
    v = run;
  }
  s[t] = v;
  __syncthreads();
  for (int off = 1; off < 1024; off <<= 1) {
    int a = (t >= off) ? s[t - off] : 0;
    __syncthreads();
    s[t] += a;
    __syncthreads();
  }
  if (idx < N_NODES) rowptr[idx] = s[t] - v;  // local exclusive
  if (t == 1023) partial[blockIdx.x] = s[1023];
}

__global__ void k_scan2(int* __restrict__ partial, int* __restrict__ rowptr) {
  __shared__ int s[64];
  int t = threadIdx.x;  // 64 threads, 1 block
  const int NB = (N_NODES + 1023) / 1024;
  int v = (t < NB) ? partial[t] : 0;
  s[t] = v;
  __syncthreads();
  for (int off = 1; off < 64; off <<= 1) {
    int a = (t >= off) ? s[t - off] : 0;
    __syncthreads();
    s[t] += a;
    __syncthreads();
  }
  if (t < NB) partial[t] = s[t] - v;  // exclusive block offsets
  if (t == NB - 1) rowptr[N_NODES] = s[t];
}

__global__ __launch_bounds__(1024) void k_scan3(const int* __restrict__ deg,
                                                const int* __restrict__ partial,
                                                int* __restrict__ rowptr,
                                                float* __restrict__ deg_inv) {
  int idx = blockIdx.x * 1024 + threadIdx.x;
  if (idx < N_NODES) {
    rowptr[idx] += partial[blockIdx.x];
    deg_inv[idx] = 1.0f / fmaxf((float)deg[idx], 1.0f);
  }
}

// atomic-free placement: slot = rowptr[d] + copyoff[c][d] + rank[e].
// Must use the SAME blockIdx->copy mapping as k_hist.
__global__ void k_place(const int* __restrict__ src, const int* __restrict__ dst,
                        const int* __restrict__ rowptr, const int* __restrict__ deg_priv,
                        const int* __restrict__ rank, int* __restrict__ esrc) {
  int e = blockIdx.x * 256 + threadIdx.x;
  if (e < N_EDGES) {
    int c = blockIdx.x & 7;
    int d = dst[e];
    esrc[rowptr[d] + deg_priv[c * N_NODES + d] + rank[e]] = src[e];
  }
}

// ---------------- split/swizzle prep ----------------
// Interleaved row layout: [hi Kg granules | lo Kg granules]; granule kb stored
// at physical slot kb ^ (row&7) within its section.

__global__ void k_prep_x(const float* __restrict__ x, ushort_t* __restrict__ xio) {
  int g = blockIdx.x * 256 + threadIdx.x;  // granule id
  if (g >= N_NODES * 8) return;
  int row = g >> 3, kb = g & 7;
  const float* p = x + (size_t)row * F_IN + kb * 8;
  us8 H, L;
#pragma unroll
  for (int i = 0; i < 8; ++i) {
    float f = p[i];
    unsigned short hi = f2bf(f);
    H[i] = hi;
    L[i] = f2bf(f - bf2f(hi));
  }
  size_t ob = (size_t)row * 128 + (size_t)((kb ^ (row & 7)) << 3);
  *(us8*)&xio[ob] = H;
  *(us8*)&xio[ob + 64] = L;
}

// all three layers' weights; W kept as separate hi/lo arrays (side-major).
__global__ void k_prep_w(const float* __restrict__ w1lp, const float* __restrict__ w1rp,
                         const float* __restrict__ w2lp, const float* __restrict__ w2rp,
                         const float* __restrict__ w3lp, const float* __restrict__ w3rp,
                         ushort_t* __restrict__ w1h, ushort_t* __restrict__ w1l,
                         ushort_t* __restrict__ w2h, ushort_t* __restrict__ w2l,
                         ushort_t* __restrict__ w3h, ushort_t* __restrict__ w3l) {
  int layer = blockIdx.z, side = blockIdx.y;
  const int Kg = (layer == 0) ? 8 : 32;
  int g = blockIdx.x * 256 + threadIdx.x;
  if (g >= 256 * Kg) return;
  const float* src = (layer == 0) ? (side ? w1rp : w1lp)
                   : (layer == 1) ? (side ? w2rp : w2lp)
                                  : (side ? w3rp : w3lp);
  ushort_t* dh = (layer == 0) ? w1h : (layer == 1) ? w2h : w3h;
  ushort_t* dl = (layer == 0) ? w1l : (layer == 1) ? w2l : w3l;
  int row = g / Kg, kb = g % Kg;
  const float* p = src + (size_t)row * (Kg * 8) + kb * 8;
  us8 H, L;
#pragma unroll
  for (int i = 0; i < 8; ++i) {
    float f = p[i];
    unsigned short hi = f2bf(f);
    H[i] = hi;
    L[i] = f2bf(f - bf2f(hi));
  }
  size_t ob = ((size_t)(side * 256 + row) * Kg + (kb ^ (row & 7))) * 8;
  *(us8*)&dh[ob] = H;
  *(us8*)&dl[ob] = L;
}

// ---------------- aggregation (gather over CSR), latency-unrolled ----------------

__global__ __launch_bounds__(256) void k_agg64s(const float* __restrict__ x,
                                                const int* __restrict__ rowptr,
                                                const int* __restrict__ esrc,
                                                const float* __restrict__ deg_inv,
                                                ushort_t* __restrict__ oio) {
  int node = blockIdx.x * 4 + (threadIdx.x >> 6);
  if (node >= N_NODES) return;
  int lane = threadIdx.x & 63;
  int e0 = rowptr[node], e1 = rowptr[node + 1];
  float acc = 0.f;
  int e = e0;
  for (; e + 4 <= e1; e += 4) {
    int s0 = esrc[e], s1 = esrc[e + 1], s2 = esrc[e + 2], s3 = esrc[e + 3];
    float v0 = x[(size_t)s0 * F_IN + lane];
    float v1 = x[(size_t)s1 * F_IN + lane];
    float v2 = x[(size_t)s2 * F_IN + lane];
    float v3 = x[(size_t)s3 * F_IN + lane];
    acc += v0 + v1 + v2 + v3;
  }
  for (; e < e1; ++e) acc += x[(size_t)esrc[e] * F_IN + lane];
  acc *= deg_inv[node];
  unsigned short hi = f2bf(acc);
  unsigned short lo = f2bf(acc - bf2f(hi));
  size_t rb = (size_t)node * 128;
  int slot = ((lane >> 3) ^ (node & 7)) << 3;
  oio[rb + slot + (lane & 7)] = hi;
  oio[rb + 64 + slot + (lane & 7)] = lo;
}

// one wave per node; single us8 load per edge covers the full 1KB hi|lo row.
// 8x/4x/1x unrolled so 4-8 gathers are in flight per wave (MLP).
__global__ __launch_bounds__(256) void k_agg256s(const ushort_t* __restrict__ hio,
                                                 const int* __restrict__ rowptr,
                                                 const int* __restrict__ esrc,
                                                 const float* __restrict__ deg_inv,
                                                 ushort_t* __restrict__ oio) {
  int node = blockIdx.x * 4 + (threadIdx.x >> 6);
  if (node >= N_NODES) return;
  int lane = threadIdx.x & 63;
  int gi = lane & 31;
  int sec = (lane >> 5) << 8;  // 0 = hi section, 256 = lo section (ushort offset)
  int e0 = rowptr[node], e1 = rowptr[node + 1];
  float a[8] = {0.f, 0.f, 0.f, 0.f, 0.f, 0.f, 0.f, 0.f};
  int e = e0;
#pragma unroll 1
  for (; e + 8 <= e1; e += 8) {
    us8 v[8];
#pragma unroll
    for (int j = 0; j < 8; ++j) {
      int s = esrc[e + j];
      v[j] = *(const us8*)&hio[(size_t)s * 512 + sec + ((gi ^ (s & 7)) << 3)];
    }
#pragma unroll
    for (int j = 0; j < 8; ++j)
#pragma unroll
      for (int i = 0; i < 8; ++i) a[i] += bf2f(v[j][i]);
  }
  if (e + 4 <= e1) {
    us8 v[4];
#pragma unroll
    for (int j = 0; j < 4; ++j) {
      int s = esrc[e + j];
      v[j] = *(const us8*)&hio[(size_t)s * 512 + sec + ((gi ^ (s & 7)) << 3)];
    }
#pragma unroll
    for (int j = 0; j < 4; ++j)
#pragma unroll
      for (int i = 0; i < 8; ++i) a[i] += bf2f(v[j][i]);
    e += 4;
  }
  for (; e < e1; ++e) {
    int s = esrc[e];
    us8 v = *(const us8*)&hio[(size_t)s * 512 + sec + ((gi ^ (s & 7)) << 3)];
#pragma unroll
    for (int i = 0; i < 8; ++i) a[i] += bf2f(v[i]);
  }
  float di = deg_inv[node];
  us8 H, L;
#pragma unroll
  for (int i = 0; i < 8; ++i) {
    float tot = (a[i] + __shfl_xor(a[i], 32)) * di;
    unsigned short hi = f2bf(tot);
    H[i] = hi;
    L[i] = f2bf(tot - bf2f(hi));
  }
  size_t rb = (size_t)node * 512 + (size_t)((gi ^ (node & 7)) << 3);
  if (lane < 32) *(us8*)&oio[rb] = H;
  else           *(us8*)&oio[rb + 256] = L;
}

// ---------------- split-bf16 MFMA GEMM ----------------
// out = relu(A1@W1^T + A2@W2^T + b). A interleaved [M_PAD][hi Kg | lo Kg] granules.
// W: [2*256, Kg] granules split hi/lo arrays. Tile 128x128, BK=64, 4 waves.

__global__ __launch_bounds__(256) void k_gemm_mfma(
    const ushort_t* __restrict__ A1, int k1g,
    const ushort_t* __restrict__ w1h, const ushort_t* __restrict__ w1l,
    const ushort_t* __restrict__ A2, int k2g,
    const ushort_t* __restrict__ w2h, const ushort_t* __restrict__ w2l,
    const float* __restrict__ bias, ushort_t* __restrict__ oio,
    float* __restrict__ ofp, int mode) {
  __shared__ __align__(16) ushort_t lds[4][8192];  // Ahi Alo Whi Wlo, 16KB each

  int t = threadIdx.x;
  int wv = t >> 6, lane = t & 63;
  int wr = wv >> 1, wc = wv & 1;
  int fr = lane & 15, kq = lane >> 4;
  int bm = blockIdx.x, bn = blockIdx.y;
  int rowA0 = bm * 128, rowW0 = bn * 128;

  f32x4 acc[4][4];
#pragma unroll
  for (int m = 0; m < 4; ++m)
#pragma unroll
    for (int n = 0; n < 4; ++n) acc[m][n] = (f32x4)0.f;

  const int ns1 = k1g >> 3, ns2 = k2g >> 3;
  const int lrow = wv * 32 + (lane >> 3);
  const int lj = lane & 7;

  for (int s = 0; s < ns1 + ns2; ++s) {
    const bool p2 = (s >= ns1);
    const ushort_t* A  = p2 ? A2 : A1;
    const ushort_t* Wh = p2 ? w2h : w1h;
    const ushort_t* Wl = p2 ? w2l : w1l;
    const int Kg = p2 ? k2g : k1g;
    const int ksg = (p2 ? (s - ns1) : s) * 8;

#pragma unroll
    for (int i = 0; i < 4; ++i) {
      int row = lrow + i * 8;
      size_t offA = ((size_t)(rowA0 + row) * (Kg * 2) + ksg + lj) * 8;
      size_t offW = ((size_t)(rowW0 + row) * Kg + ksg + lj) * 8;
      int lo = (wv * 256 + i * 64) * 8;
      gload16(A + offA, &lds[0][lo]);
      gload16(A + offA + (size_t)Kg * 8, &lds[1][lo]);
      gload16(Wh + offW, &lds[2][lo]);
      gload16(Wl + offW, &lds[3][lo]);
    }
    __syncthreads();  // drains vmcnt -> LDS tile ready

#pragma unroll
    for (int kc = 0; kc < 2; ++kc) {
      us8 ah[4], al[4], bh[4], bl[4];
      int kg = kc * 4 + kq;
      int swk = (kg ^ (fr & 7)) << 3;
#pragma unroll
      for (int m = 0; m < 4; ++m) {
        int off = ((wr * 64 + m * 16 + fr) << 6) + swk;
        ah[m] = *(const us8*)&lds[0][off];
        al[m] = *(const us8*)&lds[1][off];
      }
#pragma unroll
      for (int n = 0; n < 4; ++n) {
        int off = ((wc * 64 + n * 16 + fr) << 6) + swk;
        bh[n] = *(const us8*)&lds[2][off];
        bl[n] = *(const us8*)&lds[3][off];
      }
#pragma unroll
      for (int m = 0; m < 4; ++m)
#pragma unroll
        for (int n = 0; n < 4; ++n) {
          acc[m][n] = mfma_bf16(ah[m], bh[n], acc[m][n]);
          acc[m][n] = mfma_bf16(ah[m], bl[n], acc[m][n]);
          acc[m][n] = mfma_bf16(al[m], bh[n], acc[m][n]);
        }
    }
    __syncthreads();
  }

  // epilogue: C/D map col=lane&15, row=(lane>>4)*4+reg
#pragma unroll
  for (int n = 0; n < 4; ++n) {
    int colg = bn * 128 + wc * 64 + n * 16 + fr;
    float bv = bias[colg];
#pragma unroll
    for (int m = 0; m < 4; ++m) {
      f32x4 v = acc[m][n];
      int rowb = bm * 128 + wr * 64 + m * 16 + kq * 4;
#pragma unroll
      for (int r = 0; r < 4; ++r) {
        int rowg = rowb + r;
        if (rowg < N_NODES) {
          float h = fmaxf(v[r] + bv, 0.f);
          if (mode == 0) {
            unsigned short hi = f2bf(h);
            unsigned short lo = f2bf(h - bf2f(hi));
            int kbs = ((colg >> 3) ^ (rowg & 7)) << 3;
            size_t rb = (size_t)rowg * 512;
            oio[rb + kbs + (colg & 7)] = hi;
            oio[rb + 256 + kbs + (colg & 7)] = lo;
          } else {
            ofp[(size_t)rowg * HID + colg] = h;
          }
        }
      }
    }
  }
}

// ---------------- global mean pool (parallel over graph x chunk) ----------------

__global__ __launch_bounds__(256) void k_pool(const float* __restrict__ h,
                                              const int* __restrict__ gofs,
                                              float* __restrict__ pooled) {
  int g = blockIdx.y, c = blockIdx.x;  // 16 chunks
  int r0 = gofs[g], r1 = gofs[g + 1];
  int rg = threadIdx.x >> 6, lane = threadIdx.x & 63;
  float ax = 0.f, ay = 0.f, az = 0.f, aw = 0.f;
  for (int r = r0 + c * 4 + rg; r < r1; r += 64) {
    float4 v = *(const float4*)&h[(size_t)r * HID + lane * 4];
    ax += v.x; ay += v.y; az += v.z; aw += v.w;
  }
  __shared__ float4 sm[4][64];
  sm[rg][lane] = make_float4(ax, ay, az, aw);
  __syncthreads();
  if (rg == 0) {
    float4 s0 = sm[0][lane], s1 = sm[1][lane], s2 = sm[2][lane], s3 = sm[3][lane];
    float* p = &pooled[g * HID + lane * 4];
    atomicAdd(p + 0, s0.x + s1.x + s2.x + s3.x);
    atomicAdd(p + 1, s0.y + s1.y + s2.y + s3.y);
    atomicAdd(p + 2, s0.z + s1.z + s2.z + s3.z);
    atomicAdd(p + 3, s0.w + s1.w + s2.w + s3.w);
  }
}

// ---------------- head ----------------

__global__ __launch_bounds__(128) void k_head(const float* __restrict__ pooled,
                                              const int* __restrict__ gofs,
                                              const float* __restrict__ w1,
                                              const float* __restrict__ b1,
                                              const float* __restrict__ w2,
                                              const float* __restrict__ b2,
                                              float* __restrict__ out) {
  __shared__ float p[HID];
  __shared__ float g1[HID / 2];
  int g = blockIdx.x, t = threadIdx.x;
  float inv = 1.f / fmaxf((float)(gofs[g + 1] - gofs[g]), 1.f);
  p[t] = pooled[g * HID + t] * inv;
  p[t + 128] = pooled[g * HID + 128 + t] * inv;
  __syncthreads();
  float s = b1[t];
#pragma unroll 4
  for (int k = 0; k < HID; ++k) s = fmaf(p[k], w1[t * HID + k], s);
  g1[t] = fmaxf(s, 0.f);
  __syncthreads();
  if (t < N_OUT) {
    float s2 = b2[t];
#pragma unroll 4
    for (int k = 0; k < HID / 2; ++k) s2 = fmaf(g1[k], w2[t * (HID / 2) + k], s2);
    out[g * N_OUT + t] = s2;
  }
}

// ---------------- launch ----------------

extern "C" void kernel_launch(void* const* d_in, const int* in_sizes, int n_in,
                              void* d_out, int out_size, void* d_ws, size_t ws_size,
                              hipStream_t stream) {
  const float* x      = (const float*)d_in[0];
  const int*   ei     = (const int*)d_in[1];
  const int*   batch  = (const int*)d_in[2];
  const float* w1lw   = (const float*)d_in[3];
  const float* b1     = (const float*)d_in[4];
  const float* w1rw   = (const float*)d_in[5];
  const float* w2lw   = (const float*)d_in[6];
  const float* b2     = (const float*)d_in[7];
  const float* w2rw   = (const float*)d_in[8];
  const float* w3lw   = (const float*)d_in[9];
  const float* b3     = (const float*)d_in[10];
  const float* w3rw   = (const float*)d_in[11];
  const float* lin1_w = (const float*)d_in[12];
  const float* lin1_b = (const float*)d_in[13];
  const float* lin2_w = (const float*)d_in[14];
  const float* lin2_b = (const float*)d_in[15];
  float* out = (float*)d_out;

  const int* srcIdx = ei;
  const int* dstIdx = ei + N_EDGES;

  size_t off = 0;
  auto carve = [&](size_t bytes) {
    size_t r = off;
    off += (bytes + 255) & ~(size_t)255;
    return r;
  };
  char* ws = (char*)d_ws;
  int*      deg_priv = (int*)(ws + carve((size_t)8 * N_NODES * 4));
  int*      deg      = (int*)(ws + carve((size_t)N_NODES * 4));
  int*      rank     = (int*)(ws + carve((size_t)N_EDGES * 4));
  int*      rowptr   = (int*)(ws + carve((size_t)(N_NODES + 1) * 4));
  float*    deg_inv  = (float*)(ws + carve((size_t)N_NODES * 4));
  int*      esrc     = (int*)(ws + carve((size_t)N_EDGES * 4));
  int*      partial  = (int*)(ws + carve(64 * 4));
  int*      gofs     = (int*)(ws + carve((N_GRAPHS + 1) * 4));
  ushort_t* xio      = (ushort_t*)(ws + carve((size_t)M_PAD * 128 * 2));
  ushort_t* agg      = (ushort_t*)(ws + carve((size_t)M_PAD * 512 * 2));
  char*     h1blk    = ws + carve((size_t)M_PAD * 512 * 2);  // h1 bf16-pair OR h3 fp32
  ushort_t* h1       = (ushort_t*)h1blk;
  float*    h3       = (float*)h1blk;  // alias: h1 dead before gemm3 writes
  ushort_t* h2       = (ushort_t*)(ws + carve((size_t)M_PAD * 512 * 2));
  ushort_t* w1hi     = (ushort_t*)(ws + carve((size_t)2 * 256 * F_IN * 2));
  ushort_t* w1lo     = (ushort_t*)(ws + carve((size_t)2 * 256 * F_IN * 2));
  ushort_t* w2hi     = (ushort_t*)(ws + carve((size_t)2 * 256 * HID * 2));
  ushort_t* w2lo     = (ushort_t*)(ws + carve((size_t)2 * 256 * HID * 2));
  ushort_t* w3hi     = (ushort_t*)(ws + carve((size_t)2 * 256 * HID * 2));
  ushort_t* w3lo     = (ushort_t*)(ws + carve((size_t)2 * 256 * HID * 2));
  float*    pooled   = (float*)(ws + carve((size_t)N_GRAPHS * HID * 4));
  (void)ws_size; (void)n_in; (void)in_sizes; (void)out_size;

  hipMemsetAsync(deg_priv, 0, (size_t)8 * N_NODES * 4, stream);
  hipMemsetAsync(pooled, 0, (size_t)N_GRAPHS * HID * 4, stream);

  const int EB = (N_EDGES + 255) / 256;
  const int SB = (N_NODES + 1023) / 1024;

  k_hist<<<EB, 256, 0, stream>>>(dstIdx, deg_priv, rank);
  k_gofs<<<1, 256, 0, stream>>>(batch, gofs);
  k_scan1<<<SB, 1024, 0, stream>>>(deg_priv, deg, rowptr, partial);
  k_scan2<<<1, 64, 0, stream>>>(partial, rowptr);
  k_scan3<<<SB, 1024, 0, stream>>>(deg, partial, rowptr, deg_inv);
  k_place<<<EB, 256, 0, stream>>>(srcIdx, dstIdx, rowptr, deg_priv, rank, esrc);

  k_prep_x<<<(N_NODES * 8 + 255) / 256, 256, 0, stream>>>(x, xio);
  k_prep_w<<<dim3(32, 2, 3), 256, 0, stream>>>(w1lw, w1rw, w2lw, w2rw, w3lw, w3rw,
                                               w1hi, w1lo, w2hi, w2lo, w3hi, w3lo);

  dim3 ggrid((N_NODES + 127) / 128, 2);
  const int AB = N_NODES / 4;

  // layer 1
  k_agg64s<<<AB, 256, 0, stream>>>(x, rowptr, esrc, deg_inv, agg);
  k_gemm_mfma<<<ggrid, 256, 0, stream>>>(agg, 8, w1hi, w1lo,
                                         xio, 8, w1hi + 256 * F_IN, w1lo + 256 * F_IN,
                                         b1, h1, nullptr, 0);
  // layer 2
  k_agg256s<<<AB, 256, 0, stream>>>(h1, rowptr, esrc, deg_inv, agg);
  k_gemm_mfma<<<ggrid, 256, 0, stream>>>(agg, 32, w2hi, w2lo,
                                         h1, 32, w2hi + 256 * HID, w2lo + 256 * HID,
                                         b2, h2, nullptr, 0);
  // layer 3 (fp32 out for pooling; h3 aliases dead h1)
  k_agg256s<<<AB, 256, 0, stream>>>(h2, rowptr, esrc, deg_inv, agg);
  k_gemm_mfma<<<ggrid, 256, 0, stream>>>(agg, 32, w3hi, w3lo,
                                         h2, 32, w3hi + 256 * HID, w3lo + 256 * HID,
                                         b3, nullptr, h3, 1);

  k_pool<<<dim3(16, N_GRAPHS), 256, 0, stream>>>(h3, gofs, pooled);
  k_head<<<N_GRAPHS, 128, 0, stream>>>(pooled, gofs, lin1_w, lin1_b, lin2_w, lin2_b, out);
}

// Round 6
// 434.522 us; speedup vs baseline: 2.7673x; 1.2689x over previous
//
#include <hip/hip_runtime.h>

#define N_NODES 50000
#define M_PAD   50048   // padded rows so global_load_lds never reads past buffers
#define N_EDGES 800000
#define F_IN 64
#define HID 256
#define N_GRAPHS 128
#define N_OUT 24

typedef unsigned short ushort_t;
typedef __attribute__((ext_vector_type(8))) unsigned short us8;
typedef __attribute__((ext_vector_type(8))) __bf16 bf16x8;
typedef __attribute__((ext_vector_type(4))) float f32x4;

__device__ __forceinline__ unsigned short f2bf(float f) {
  unsigned u = __builtin_bit_cast(unsigned, f);
  return (unsigned short)((u + 0x7fffu + ((u >> 16) & 1u)) >> 16);
}
__device__ __forceinline__ float bf2f(unsigned short h) {
  return __builtin_bit_cast(float, (unsigned)h << 16);
}

__device__ __forceinline__ f32x4 mfma_bf16(us8 a, us8 b, f32x4 c) {
  return __builtin_amdgcn_mfma_f32_16x16x32_bf16(
      __builtin_bit_cast(bf16x8, a), __builtin_bit_cast(bf16x8, b), c, 0, 0, 0);
}

__device__ __forceinline__ void gload16(const ushort_t* g, ushort_t* l) {
  __builtin_amdgcn_global_load_lds(
      (const __attribute__((address_space(1))) void*)g,
      (__attribute__((address_space(3))) void*)l, 16, 0, 0);
}

// ---------------- CSR build (privatized histogram, atomic-free scatter) ----------------

// 8-way privatized degree histogram; records each edge's rank within (copy,dst).
__global__ void k_hist(const int* __restrict__ dst, int* __restrict__ deg_priv,
                       int* __restrict__ rank) {
  int e = blockIdx.x * 256 + threadIdx.x;
  if (e < N_EDGES) {
    int c = blockIdx.x & 7;
    rank[e] = atomicAdd(&deg_priv[c * N_NODES + dst[e]], 1);
  }
}

// batch is sorted: gofs[g] = first index with batch[i] >= g (binary search, no atomics).
__global__ void k_gofs(const int* __restrict__ batch, int* __restrict__ gofs) {
  int t = threadIdx.x;
  if (t > N_GRAPHS) return;
  int lo = 0, hi = N_NODES;
  while (lo < hi) {
    int mid = (lo + hi) >> 1;
    if (batch[mid] < t) lo = mid + 1;
    else hi = mid;
  }
  gofs[t] = lo;
}

// fused: reduce 8 copies -> per-copy exclusive offsets (in place) + total deg,
// then block-local exclusive scan of deg.
__global__ __launch_bounds__(1024) void k_scan1(int* __restrict__ deg_priv,
                                                int* __restrict__ deg,
                                                int* __restrict__ rowptr,
                                                int* __restrict__ partial) {
  __shared__ int s[1024];
  int t = threadIdx.x;
  int idx = blockIdx.x * 1024 + t;
  int v = 0;
  if (idx < N_NODES) {
    int run = 0;
#pragma unroll
    for (int c = 0; c < 8; ++c) {
      int dv = deg_priv[c * N_NODES + idx];
      deg_priv[c * N_NODES + idx] = run;  // exclusive offset among copies
      run += dv;
    }
    deg[idx] = run;
    v = run;
  }
  s[t] = v;
  __syncthreads();
  for (int off = 1; off < 1024; off <<= 1) {
    int a = (t >= off) ? s[t - off] : 0;
    __syncthreads();
    s[t] += a;
    __syncthreads();
  }
  if (idx < N_NODES) rowptr[idx] = s[t] - v;  // local exclusive
  if (t == 1023) partial[blockIdx.x] = s[1023];
}

__global__ void k_scan2(int* __restrict__ partial, int* __restrict__ rowptr) {
  __shared__ int s[64];
  int t = threadIdx.x;  // 64 threads, 1 block
  const int NB = (N_NODES + 1023) / 1024;
  int v = (t < NB) ? partial[t] : 0;
  s[t] = v;
  __syncthreads();
  for (int off = 1; off < 64; off <<= 1) {
    int a = (t >= off) ? s[t - off] : 0;
    __syncthreads();
    s[t] += a;
    __syncthreads();
  }
  if (t < NB) partial[t] = s[t] - v;  // exclusive block offsets
  if (t == NB - 1) rowptr[N_NODES] = s[t];
}

__global__ __launch_bounds__(1024) void k_scan3(const int* __restrict__ deg,
                                                const int* __restrict__ partial,
                                                int* __restrict__ rowptr,
                                                float* __restrict__ deg_inv) {
  int idx = blockIdx.x * 1024 + threadIdx.x;
  if (idx < N_NODES) {
    rowptr[idx] += partial[blockIdx.x];
    deg_inv[idx] = 1.0f / fmaxf((float)deg[idx], 1.0f);
  }
}

// atomic-free placement: slot = rowptr[d] + copyoff[c][d] + rank[e].
// Must use the SAME blockIdx->copy mapping as k_hist.
__global__ void k_place(const int* __restrict__ src, const int* __restrict__ dst,
                        const int* __restrict__ rowptr, const int* __restrict__ deg_priv,
                        const int* __restrict__ rank, int* __restrict__ esrc) {
  int e = blockIdx.x * 256 + threadIdx.x;
  if (e < N_EDGES) {
    int c = blockIdx.x & 7;
    int d = dst[e];
    esrc[rowptr[d] + deg_priv[c * N_NODES + d] + rank[e]] = src[e];
  }
}

// ---------------- split/swizzle prep ----------------
// Interleaved row layout: [hi Kg granules | lo Kg granules]; granule kb stored
// at physical slot kb ^ (row&7) within its section.

__global__ void k_prep_x(const float* __restrict__ x, ushort_t* __restrict__ xio) {
  int g = blockIdx.x * 256 + threadIdx.x;  // granule id
  if (g >= N_NODES * 8) return;
  int row = g >> 3, kb = g & 7;
  const float* p = x + (size_t)row * F_IN + kb * 8;
  us8 H, L;
#pragma unroll
  for (int i = 0; i < 8; ++i) {
    float f = p[i];
    unsigned short hi = f2bf(f);
    H[i] = hi;
    L[i] = f2bf(f - bf2f(hi));
  }
  size_t ob = (size_t)row * 128 + (size_t)((kb ^ (row & 7)) << 3);
  *(us8*)&xio[ob] = H;
  *(us8*)&xio[ob + 64] = L;
}

// all three layers' weights; W kept as separate hi/lo arrays (side-major).
__global__ void k_prep_w(const float* __restrict__ w1lp, const float* __restrict__ w1rp,
                         const float* __restrict__ w2lp, const float* __restrict__ w2rp,
                         const float* __restrict__ w3lp, const float* __restrict__ w3rp,
                         ushort_t* __restrict__ w1h, ushort_t* __restrict__ w1l,
                         ushort_t* __restrict__ w2h, ushort_t* __restrict__ w2l,
                         ushort_t* __restrict__ w3h, ushort_t* __restrict__ w3l) {
  int layer = blockIdx.z, side = blockIdx.y;
  const int Kg = (layer == 0) ? 8 : 32;
  int g = blockIdx.x * 256 + threadIdx.x;
  if (g >= 256 * Kg) return;
  const float* src = (layer == 0) ? (side ? w1rp : w1lp)
                   : (layer == 1) ? (side ? w2rp : w2lp)
                                  : (side ? w3rp : w3lp);
  ushort_t* dh = (layer == 0) ? w1h : (layer == 1) ? w2h : w3h;
  ushort_t* dl = (layer == 0) ? w1l : (layer == 1) ? w2l : w3l;
  int row = g / Kg, kb = g % Kg;
  const float* p = src + (size_t)row * (Kg * 8) + kb * 8;
  us8 H, L;
#pragma unroll
  for (int i = 0; i < 8; ++i) {
    float f = p[i];
    unsigned short hi = f2bf(f);
    H[i] = hi;
    L[i] = f2bf(f - bf2f(hi));
  }
  size_t ob = ((size_t)(side * 256 + row) * Kg + (kb ^ (row & 7))) * 8;
  *(us8*)&dh[ob] = H;
  *(us8*)&dl[ob] = L;
}

// ---------------- aggregation (gather over CSR) ----------------

__global__ __launch_bounds__(256) void k_agg64s(const float* __restrict__ x,
                                                const int* __restrict__ rowptr,
                                                const int* __restrict__ esrc,
                                                const float* __restrict__ deg_inv,
                                                ushort_t* __restrict__ oio) {
  int node = blockIdx.x * 4 + (threadIdx.x >> 6);
  if (node >= N_NODES) return;
  int lane = threadIdx.x & 63;
  int e0 = rowptr[node], e1 = rowptr[node + 1];
  float acc = 0.f;
  int e = e0;
  for (; e + 4 <= e1; e += 4) {
    int s0 = esrc[e], s1 = esrc[e + 1], s2 = esrc[e + 2], s3 = esrc[e + 3];
    float v0 = x[(size_t)s0 * F_IN + lane];
    float v1 = x[(size_t)s1 * F_IN + lane];
    float v2 = x[(size_t)s2 * F_IN + lane];
    float v3 = x[(size_t)s3 * F_IN + lane];
    acc += v0 + v1 + v2 + v3;
  }
  for (; e < e1; ++e) acc += x[(size_t)esrc[e] * F_IN + lane];
  acc *= deg_inv[node];
  unsigned short hi = f2bf(acc);
  unsigned short lo = f2bf(acc - bf2f(hi));
  size_t rb = (size_t)node * 128;
  int slot = ((lane >> 3) ^ (node & 7)) << 3;
  oio[rb + slot + (lane & 7)] = hi;
  oio[rb + 64 + slot + (lane & 7)] = lo;
}

// one wave per node; hi-only gather (2B/feature): half-wave per edge, 512B per
// half-wave (16B/lane). Neighbor values are bf16-rounded (mean-of-16 keeps the
// added error ~1e-4 abs, well under threshold). 4-pair unroll for MLP.
__global__ __launch_bounds__(256) void k_agg256s(const ushort_t* __restrict__ hio,
                                                 const int* __restrict__ rowptr,
                                                 const int* __restrict__ esrc,
                                                 const float* __restrict__ deg_inv,
                                                 ushort_t* __restrict__ oio) {
  int node = blockIdx.x * 4 + (threadIdx.x >> 6);
  if (node >= N_NODES) return;
  int lane = threadIdx.x & 63;
  int gi = lane & 31;       // granule within hi section
  int half = lane >> 5;     // 0: even edges, 1: odd edges
  int e0 = rowptr[node], e1 = rowptr[node + 1];
  float a[8] = {0.f, 0.f, 0.f, 0.f, 0.f, 0.f, 0.f, 0.f};
  int e = e0;
#pragma unroll 1
  for (; e + 8 <= e1; e += 8) {
    us8 v[4];
#pragma unroll
    for (int j = 0; j < 4; ++j) {
      int s = esrc[e + 2 * j + half];
      v[j] = *(const us8*)&hio[(size_t)s * 512 + ((gi ^ (s & 7)) << 3)];
    }
#pragma unroll
    for (int j = 0; j < 4; ++j)
#pragma unroll
      for (int i = 0; i < 8; ++i) a[i] += bf2f(v[j][i]);
  }
#pragma unroll 1
  for (; e + 2 <= e1; e += 2) {
    int s = esrc[e + half];
    us8 v = *(const us8*)&hio[(size_t)s * 512 + ((gi ^ (s & 7)) << 3)];
#pragma unroll
    for (int i = 0; i < 8; ++i) a[i] += bf2f(v[i]);
  }
  if (e < e1 && half == 0) {  // single leftover edge: lanes 0-31 only
    int s = esrc[e];
    us8 v = *(const us8*)&hio[(size_t)s * 512 + ((gi ^ (s & 7)) << 3)];
#pragma unroll
    for (int i = 0; i < 8; ++i) a[i] += bf2f(v[i]);
  }
  float di = deg_inv[node];
  us8 H, L;
#pragma unroll
  for (int i = 0; i < 8; ++i) {
    float tot = (a[i] + __shfl_xor(a[i], 32)) * di;
    unsigned short hi = f2bf(tot);
    H[i] = hi;
    L[i] = f2bf(tot - bf2f(hi));
  }
  size_t rb = (size_t)node * 512 + (size_t)((gi ^ (node & 7)) << 3);
  if (lane < 32) *(us8*)&oio[rb] = H;
  else           *(us8*)&oio[rb + 256] = L;
}

// ---------------- split-bf16 MFMA GEMM ----------------
// out = relu(A1@W1^T + A2@W2^T + b). A interleaved [M_PAD][hi Kg | lo Kg] granules.
// W: [2*256, Kg] granules split hi/lo arrays. Tile 128x128, BK=64, 4 waves.

__global__ __launch_bounds__(256) void k_gemm_mfma(
    const ushort_t* __restrict__ A1, int k1g,
    const ushort_t* __restrict__ w1h, const ushort_t* __restrict__ w1l,
    const ushort_t* __restrict__ A2, int k2g,
    const ushort_t* __restrict__ w2h, const ushort_t* __restrict__ w2l,
    const float* __restrict__ bias, ushort_t* __restrict__ oio,
    float* __restrict__ ofp, int mode) {
  __shared__ __align__(16) ushort_t lds[4][8192];  // Ahi Alo Whi Wlo, 16KB each

  int t = threadIdx.x;
  int wv = t >> 6, lane = t & 63;
  int wr = wv >> 1, wc = wv & 1;
  int fr = lane & 15, kq = lane >> 4;
  int bm = blockIdx.x, bn = blockIdx.y;
  int rowA0 = bm * 128, rowW0 = bn * 128;

  f32x4 acc[4][4];
#pragma unroll
  for (int m = 0; m < 4; ++m)
#pragma unroll
    for (int n = 0; n < 4; ++n) acc[m][n] = (f32x4)0.f;

  const int ns1 = k1g >> 3, ns2 = k2g >> 3;
  const int lrow = wv * 32 + (lane >> 3);
  const int lj = lane & 7;

  for (int s = 0; s < ns1 + ns2; ++s) {
    const bool p2 = (s >= ns1);
    const ushort_t* A  = p2 ? A2 : A1;
    const ushort_t* Wh = p2 ? w2h : w1h;
    const ushort_t* Wl = p2 ? w2l : w1l;
    const int Kg = p2 ? k2g : k1g;
    const int ksg = (p2 ? (s - ns1) : s) * 8;

#pragma unroll
    for (int i = 0; i < 4; ++i) {
      int row = lrow + i * 8;
      size_t offA = ((size_t)(rowA0 + row) * (Kg * 2) + ksg + lj) * 8;
      size_t offW = ((size_t)(rowW0 + row) * Kg + ksg + lj) * 8;
      int lo = (wv * 256 + i * 64) * 8;
      gload16(A + offA, &lds[0][lo]);
      gload16(A + offA + (size_t)Kg * 8, &lds[1][lo]);
      gload16(Wh + offW, &lds[2][lo]);
      gload16(Wl + offW, &lds[3][lo]);
    }
    __syncthreads();  // drains vmcnt -> LDS tile ready

#pragma unroll
    for (int kc = 0; kc < 2; ++kc) {
      us8 ah[4], al[4], bh[4], bl[4];
      int kg = kc * 4 + kq;
      int swk = (kg ^ (fr & 7)) << 3;
#pragma unroll
      for (int m = 0; m < 4; ++m) {
        int off = ((wr * 64 + m * 16 + fr) << 6) + swk;
        ah[m] = *(const us8*)&lds[0][off];
        al[m] = *(const us8*)&lds[1][off];
      }
#pragma unroll
      for (int n = 0; n < 4; ++n) {
        int off = ((wc * 64 + n * 16 + fr) << 6) + swk;
        bh[n] = *(const us8*)&lds[2][off];
        bl[n] = *(const us8*)&lds[3][off];
      }
#pragma unroll
      for (int m = 0; m < 4; ++m)
#pragma unroll
        for (int n = 0; n < 4; ++n) {
          acc[m][n] = mfma_bf16(ah[m], bh[n], acc[m][n]);
          acc[m][n] = mfma_bf16(ah[m], bl[n], acc[m][n]);
          acc[m][n] = mfma_bf16(al[m], bh[n], acc[m][n]);
        }
    }
    __syncthreads();
  }

  // epilogue: C/D map col=lane&15, row=(lane>>4)*4+reg
#pragma unroll
  for (int n = 0; n < 4; ++n) {
    int colg = bn * 128 + wc * 64 + n * 16 + fr;
    float bv = bias[colg];
#pragma unroll
    for (int m = 0; m < 4; ++m) {
      f32x4 v = acc[m][n];
      int rowb = bm * 128 + wr * 64 + m * 16 + kq * 4;
#pragma unroll
      for (int r = 0; r < 4; ++r) {
        int rowg = rowb + r;
        if (rowg < N_NODES) {
          float h = fmaxf(v[r] + bv, 0.f);
          if (mode == 0) {
            unsigned short hi = f2bf(h);
            unsigned short lo = f2bf(h - bf2f(hi));
            int kbs = ((colg >> 3) ^ (rowg & 7)) << 3;
            size_t rb = (size_t)rowg * 512;
            oio[rb + kbs + (colg & 7)] = hi;
            oio[rb + 256 + kbs + (colg & 7)] = lo;
          } else {
            ofp[(size_t)rowg * HID + colg] = h;
          }
        }
      }
    }
  }
}

// ---------------- global mean pool (parallel over graph x chunk) ----------------

__global__ __launch_bounds__(256) void k_pool(const float* __restrict__ h,
                                              const int* __restrict__ gofs,
                                              float* __restrict__ pooled) {
  int g = blockIdx.y, c = blockIdx.x;  // 16 chunks
  int r0 = gofs[g], r1 = gofs[g + 1];
  int rg = threadIdx.x >> 6, lane = threadIdx.x & 63;
  float ax = 0.f, ay = 0.f, az = 0.f, aw = 0.f;
  for (int r = r0 + c * 4 + rg; r < r1; r += 64) {
    float4 v = *(const float4*)&h[(size_t)r * HID + lane * 4];
    ax += v.x; ay += v.y; az += v.z; aw += v.w;
  }
  __shared__ float4 sm[4][64];
  sm[rg][lane] = make_float4(ax, ay, az, aw);
  __syncthreads();
  if (rg == 0) {
    float4 s0 = sm[0][lane], s1 = sm[1][lane], s2 = sm[2][lane], s3 = sm[3][lane];
    float* p = &pooled[g * HID + lane * 4];
    atomicAdd(p + 0, s0.x + s1.x + s2.x + s3.x);
    atomicAdd(p + 1, s0.y + s1.y + s2.y + s3.y);
    atomicAdd(p + 2, s0.z + s1.z + s2.z + s3.z);
    atomicAdd(p + 3, s0.w + s1.w + s2.w + s3.w);
  }
}

// ---------------- head ----------------

__global__ __launch_bounds__(128) void k_head(const float* __restrict__ pooled,
                                              const int* __restrict__ gofs,
                                              const float* __restrict__ w1,
                                              const float* __restrict__ b1,
                                              const float* __restrict__ w2,
                                              const float* __restrict__ b2,
                                              float* __restrict__ out) {
  __shared__ float p[HID];
  __shared__ float g1[HID / 2];
  int g = blockIdx.x, t = threadIdx.x;
  float inv = 1.f / fmaxf((float)(gofs[g + 1] - gofs[g]), 1.f);
  p[t] = pooled[g * HID + t] * inv;
  p[t + 128] = pooled[g * HID + 128 + t] * inv;
  __syncthreads();
  float s = b1[t];
#pragma unroll 4
  for (int k = 0; k < HID; ++k) s = fmaf(p[k], w1[t * HID + k], s);
  g1[t] = fmaxf(s, 0.f);
  __syncthreads();
  if (t < N_OUT) {
    float s2 = b2[t];
#pragma unroll 4
    for (int k = 0; k < HID / 2; ++k) s2 = fmaf(g1[k], w2[t * (HID / 2) + k], s2);
    out[g * N_OUT + t] = s2;
  }
}

// ---------------- launch ----------------

extern "C" void kernel_launch(void* const* d_in, const int* in_sizes, int n_in,
                              void* d_out, int out_size, void* d_ws, size_t ws_size,
                              hipStream_t stream) {
  const float* x      = (const float*)d_in[0];
  const int*   ei     = (const int*)d_in[1];
  const int*   batch  = (const int*)d_in[2];
  const float* w1lw   = (const float*)d_in[3];
  const float* b1     = (const float*)d_in[4];
  const float* w1rw   = (const float*)d_in[5];
  const float* w2lw   = (const float*)d_in[6];
  const float* b2     = (const float*)d_in[7];
  const float* w2rw   = (const float*)d_in[8];
  const float* w3lw   = (const float*)d_in[9];
  const float* b3     = (const float*)d_in[10];
  const float* w3rw   = (const float*)d_in[11];
  const float* lin1_w = (const float*)d_in[12];
  const float* lin1_b = (const float*)d_in[13];
  const float* lin2_w = (const float*)d_in[14];
  const float* lin2_b = (const float*)d_in[15];
  float* out = (float*)d_out;

  const int* srcIdx = ei;
  const int* dstIdx = ei + N_EDGES;

  size_t off = 0;
  auto carve = [&](size_t bytes) {
    size_t r = off;
    off += (bytes + 255) & ~(size_t)255;
    return r;
  };
  char* ws = (char*)d_ws;
  int*      deg_priv = (int*)(ws + carve((size_t)8 * N_NODES * 4));
  int*      deg      = (int*)(ws + carve((size_t)N_NODES * 4));
  int*      rank     = (int*)(ws + carve((size_t)N_EDGES * 4));
  int*      rowptr   = (int*)(ws + carve((size_t)(N_NODES + 1) * 4));
  float*    deg_inv  = (float*)(ws + carve((size_t)N_NODES * 4));
  int*      esrc     = (int*)(ws + carve((size_t)N_EDGES * 4));
  int*      partial  = (int*)(ws + carve(64 * 4));
  int*      gofs     = (int*)(ws + carve((N_GRAPHS + 1) * 4));
  ushort_t* xio      = (ushort_t*)(ws + carve((size_t)M_PAD * 128 * 2));
  ushort_t* agg      = (ushort_t*)(ws + carve((size_t)M_PAD * 512 * 2));
  char*     h1blk    = ws + carve((size_t)M_PAD * 512 * 2);  // h1 bf16-pair OR h3 fp32
  ushort_t* h1       = (ushort_t*)h1blk;
  float*    h3       = (float*)h1blk;  // alias: h1 dead before gemm3 writes
  ushort_t* h2       = (ushort_t*)(ws + carve((size_t)M_PAD * 512 * 2));
  ushort_t* w1hi     = (ushort_t*)(ws + carve((size_t)2 * 256 * F_IN * 2));
  ushort_t* w1lo     = (ushort_t*)(ws + carve((size_t)2 * 256 * F_IN * 2));
  ushort_t* w2hi     = (ushort_t*)(ws + carve((size_t)2 * 256 * HID * 2));
  ushort_t* w2lo     = (ushort_t*)(ws + carve((size_t)2 * 256 * HID * 2));
  ushort_t* w3hi     = (ushort_t*)(ws + carve((size_t)2 * 256 * HID * 2));
  ushort_t* w3lo     = (ushort_t*)(ws + carve((size_t)2 * 256 * HID * 2));
  float*    pooled   = (float*)(ws + carve((size_t)N_GRAPHS * HID * 4));
  (void)ws_size; (void)n_in; (void)in_sizes; (void)out_size;

  hipMemsetAsync(deg_priv, 0, (size_t)8 * N_NODES * 4, stream);
  hipMemsetAsync(pooled, 0, (size_t)N_GRAPHS * HID * 4, stream);

  const int EB = (N_EDGES + 255) / 256;
  const int SB = (N_NODES + 1023) / 1024;

  k_hist<<<EB, 256, 0, stream>>>(dstIdx, deg_priv, rank);
  k_gofs<<<1, 256, 0, stream>>>(batch, gofs);
  k_scan1<<<SB, 1024, 0, stream>>>(deg_priv, deg, rowptr, partial);
  k_scan2<<<1, 64, 0, stream>>>(partial, rowptr);
  k_scan3<<<SB, 1024, 0, stream>>>(deg, partial, rowptr, deg_inv);
  k_place<<<EB, 256, 0, stream>>>(srcIdx, dstIdx, rowptr, deg_priv, rank, esrc);

  k_prep_x<<<(N_NODES * 8 + 255) / 256, 256, 0, stream>>>(x, xio);
  k_prep_w<<<dim3(32, 2, 3), 256, 0, stream>>>(w1lw, w1rw, w2lw, w2rw, w3lw, w3rw,
                                               w1hi, w1lo, w2hi, w2lo, w3hi, w3lo);

  dim3 ggrid((N_NODES + 127) / 128, 2);
  const int AB = N_NODES / 4;

  // layer 1
  k_agg64s<<<AB, 256, 0, stream>>>(x, rowptr, esrc, deg_inv, agg);
  k_gemm_mfma<<<ggrid, 256, 0, stream>>>(agg, 8, w1hi, w1lo,
                                         xio, 8, w1hi + 256 * F_IN, w1lo + 256 * F_IN,
                                         b1, h1, nullptr, 0);
  // layer 2
  k_agg256s<<<AB, 256, 0, stream>>>(h1, rowptr, esrc, deg_inv, agg);
  k_gemm_mfma<<<ggrid, 256, 0, stream>>>(agg, 32, w2hi, w2lo,
                                         h1, 32, w2hi + 256 * HID, w2lo + 256 * HID,
                                         b2, h2, nullptr, 0);
  // layer 3 (fp32 out for pooling; h3 aliases dead h1)
  k_agg256s<<<AB, 256, 0, stream>>>(h2, rowptr, esrc, deg_inv, agg);
  k_gemm_mfma<<<ggrid, 256, 0, stream>>>(agg, 32, w3hi, w3lo,
                                         h2, 32, w3hi + 256 * HID, w3lo + 256 * HID,
                                         b3, nullptr, h3, 1);

  k_pool<<<dim3(16, N_GRAPHS), 256, 0, stream>>>(h3, gofs, pooled);
  k_head<<<N_GRAPHS, 128, 0, stream>>>(pooled, gofs, lin1_w, lin1_b, lin2_w, lin2_b, out);
}

// Round 7
// 394.418 us; speedup vs baseline: 3.0487x; 1.1017x over previous
//
#include <hip/hip_runtime.h>

#define N_NODES 50000
#define M_PAD   50048   // padded rows so global_load_lds never reads past buffers
#define N_EDGES 800000
#define F_IN 64
#define HID 256
#define N_GRAPHS 128
#define N_OUT 24

typedef unsigned short ushort_t;
typedef __attribute__((ext_vector_type(8))) unsigned short us8;
typedef __attribute__((ext_vector_type(8))) __bf16 bf16x8;
typedef __attribute__((ext_vector_type(4))) float f32x4;

__device__ __forceinline__ unsigned short f2bf(float f) {
  unsigned u = __builtin_bit_cast(unsigned, f);
  return (unsigned short)((u + 0x7fffu + ((u >> 16) & 1u)) >> 16);
}
__device__ __forceinline__ float bf2f(unsigned short h) {
  return __builtin_bit_cast(float, (unsigned)h << 16);
}

__device__ __forceinline__ f32x4 mfma_bf16(us8 a, us8 b, f32x4 c) {
  return __builtin_amdgcn_mfma_f32_16x16x32_bf16(
      __builtin_bit_cast(bf16x8, a), __builtin_bit_cast(bf16x8, b), c, 0, 0, 0);
}

__device__ __forceinline__ void gload16(const ushort_t* g, ushort_t* l) {
  __builtin_amdgcn_global_load_lds(
      (const __attribute__((address_space(1))) void*)g,
      (__attribute__((address_space(3))) void*)l, 16, 0, 0);
}

// ---------------- CSR build (privatized histogram, atomic-free scatter) ----------------

__global__ void k_hist(const int* __restrict__ dst, int* __restrict__ deg_priv,
                       int* __restrict__ rank) {
  int e = blockIdx.x * 256 + threadIdx.x;
  if (e < N_EDGES) {
    int c = blockIdx.x & 7;
    rank[e] = atomicAdd(&deg_priv[c * N_NODES + dst[e]], 1);
  }
}

// batch is sorted: gofs[g] = first index with batch[i] >= g (binary search).
__global__ void k_gofs(const int* __restrict__ batch, int* __restrict__ gofs) {
  int t = threadIdx.x;
  if (t > N_GRAPHS) return;
  int lo = 0, hi = N_NODES;
  while (lo < hi) {
    int mid = (lo + hi) >> 1;
    if (batch[mid] < t) lo = mid + 1;
    else hi = mid;
  }
  gofs[t] = lo;
}

__global__ __launch_bounds__(1024) void k_scan1(int* __restrict__ deg_priv,
                                                int* __restrict__ deg,
                                                int* __restrict__ rowptr,
                                                int* __restrict__ partial) {
  __shared__ int s[1024];
  int t = threadIdx.x;
  int idx = blockIdx.x * 1024 + t;
  int v = 0;
  if (idx < N_NODES) {
    int run = 0;
#pragma unroll
    for (int c = 0; c < 8; ++c) {
      int dv = deg_priv[c * N_NODES + idx];
      deg_priv[c * N_NODES + idx] = run;  // exclusive offset among copies
      run += dv;
    }
    deg[idx] = run;
    v = run;
  }
  s[t] = v;
  __syncthreads();
  for (int off = 1; off < 1024; off <<= 1) {
    int a = (t >= off) ? s[t - off] : 0;
    __syncthreads();
    s[t] += a;
    __syncthreads();
  }
  if (idx < N_NODES) rowptr[idx] = s[t] - v;  // local exclusive
  if (t == 1023) partial[blockIdx.x] = s[1023];
}

__global__ void k_scan2(int* __restrict__ partial, int* __restrict__ rowptr) {
  __shared__ int s[64];
  int t = threadIdx.x;
  const int NB = (N_NODES + 1023) / 1024;
  int v = (t < NB) ? partial[t] : 0;
  s[t] = v;
  __syncthreads();
  for (int off = 1; off < 64; off <<= 1) {
    int a = (t >= off) ? s[t - off] : 0;
    __syncthreads();
    s[t] += a;
    __syncthreads();
  }
  if (t < NB) partial[t] = s[t] - v;
  if (t == NB - 1) rowptr[N_NODES] = s[t];
}

__global__ __launch_bounds__(1024) void k_scan3(const int* __restrict__ deg,
                                                const int* __restrict__ partial,
                                                int* __restrict__ rowptr,
                                                float* __restrict__ deg_inv) {
  int idx = blockIdx.x * 1024 + threadIdx.x;
  if (idx < N_NODES) {
    rowptr[idx] += partial[blockIdx.x];
    deg_inv[idx] = 1.0f / fmaxf((float)deg[idx], 1.0f);
  }
}

__global__ void k_place(const int* __restrict__ src, const int* __restrict__ dst,
                        const int* __restrict__ rowptr, const int* __restrict__ deg_priv,
                        const int* __restrict__ rank, int* __restrict__ esrc) {
  int e = blockIdx.x * 256 + threadIdx.x;
  if (e < N_EDGES) {
    int c = blockIdx.x & 7;
    int d = dst[e];
    esrc[rowptr[d] + deg_priv[c * N_NODES + d] + rank[e]] = src[e];
  }
}

// ---------------- split/swizzle prep ----------------
// x: interleaved [hi 8 granules | lo 8 granules]; granule kb at slot kb^(row&7).

__global__ void k_prep_x(const float* __restrict__ x, ushort_t* __restrict__ xio) {
  int g = blockIdx.x * 256 + threadIdx.x;
  if (g >= N_NODES * 8) return;
  int row = g >> 3, kb = g & 7;
  const float* p = x + (size_t)row * F_IN + kb * 8;
  us8 H, L;
#pragma unroll
  for (int i = 0; i < 8; ++i) {
    float f = p[i];
    unsigned short hi = f2bf(f);
    H[i] = hi;
    L[i] = f2bf(f - bf2f(hi));
  }
  size_t ob = (size_t)row * 128 + (size_t)((kb ^ (row & 7)) << 3);
  *(us8*)&xio[ob] = H;
  *(us8*)&xio[ob + 64] = L;
}

// all three layers' weights; W kept as separate hi/lo arrays (side-major).
__global__ void k_prep_w(const float* __restrict__ w1lp, const float* __restrict__ w1rp,
                         const float* __restrict__ w2lp, const float* __restrict__ w2rp,
                         const float* __restrict__ w3lp, const float* __restrict__ w3rp,
                         ushort_t* __restrict__ w1h, ushort_t* __restrict__ w1l,
                         ushort_t* __restrict__ w2h, ushort_t* __restrict__ w2l,
                         ushort_t* __restrict__ w3h, ushort_t* __restrict__ w3l) {
  int layer = blockIdx.z, side = blockIdx.y;
  const int Kg = (layer == 0) ? 8 : 32;
  int g = blockIdx.x * 256 + threadIdx.x;
  if (g >= 256 * Kg) return;
  const float* src = (layer == 0) ? (side ? w1rp : w1lp)
                   : (layer == 1) ? (side ? w2rp : w2lp)
                                  : (side ? w3rp : w3lp);
  ushort_t* dh = (layer == 0) ? w1h : (layer == 1) ? w2h : w3h;
  ushort_t* dl = (layer == 0) ? w1l : (layer == 1) ? w2l : w3l;
  int row = g / Kg, kb = g % Kg;
  const float* p = src + (size_t)row * (Kg * 8) + kb * 8;
  us8 H, L;
#pragma unroll
  for (int i = 0; i < 8; ++i) {
    float f = p[i];
    unsigned short hi = f2bf(f);
    H[i] = hi;
    L[i] = f2bf(f - bf2f(hi));
  }
  size_t ob = ((size_t)(side * 256 + row) * Kg + (kb ^ (row & 7))) * 8;
  *(us8*)&dh[ob] = H;
  *(us8*)&dl[ob] = L;
}

// ---------------- aggregation (gather over CSR) ----------------

// layer-1 agg: fp32 x gather -> split hi/lo interleaved (Kg=8) for 3-term GEMM.
__global__ __launch_bounds__(256) void k_agg64s(const float* __restrict__ x,
                                                const int* __restrict__ rowptr,
                                                const int* __restrict__ esrc,
                                                const float* __restrict__ deg_inv,
                                                ushort_t* __restrict__ oio) {
  int node = blockIdx.x * 4 + (threadIdx.x >> 6);
  if (node >= N_NODES) return;
  int lane = threadIdx.x & 63;
  int e0 = rowptr[node], e1 = rowptr[node + 1];
  float acc = 0.f;
  int e = e0;
  for (; e + 4 <= e1; e += 4) {
    int s0 = esrc[e], s1 = esrc[e + 1], s2 = esrc[e + 2], s3 = esrc[e + 3];
    float v0 = x[(size_t)s0 * F_IN + lane];
    float v1 = x[(size_t)s1 * F_IN + lane];
    float v2 = x[(size_t)s2 * F_IN + lane];
    float v3 = x[(size_t)s3 * F_IN + lane];
    acc += v0 + v1 + v2 + v3;
  }
  for (; e < e1; ++e) acc += x[(size_t)esrc[e] * F_IN + lane];
  acc *= deg_inv[node];
  unsigned short hi = f2bf(acc);
  unsigned short lo = f2bf(acc - bf2f(hi));
  size_t rb = (size_t)node * 128;
  int slot = ((lane >> 3) ^ (node & 7)) << 3;
  oio[rb + slot + (lane & 7)] = hi;
  oio[rb + 64 + slot + (lane & 7)] = lo;
}

// layers 2/3: h rows are plain bf16-hi, 256 ushort (32 swizzled granules).
// Half-wave per edge (32 lanes x 16B = 512B row); combine halves via shfl.
__global__ __launch_bounds__(256) void k_agg256s(const ushort_t* __restrict__ hio,
                                                 const int* __restrict__ rowptr,
                                                 const int* __restrict__ esrc,
                                                 const float* __restrict__ deg_inv,
                                                 ushort_t* __restrict__ oio) {
  int node = blockIdx.x * 4 + (threadIdx.x >> 6);
  if (node >= N_NODES) return;
  int lane = threadIdx.x & 63;
  int gi = lane & 31;       // granule within row
  int half = lane >> 5;     // 0: even edges, 1: odd edges
  int e0 = rowptr[node], e1 = rowptr[node + 1];
  float a[8] = {0.f, 0.f, 0.f, 0.f, 0.f, 0.f, 0.f, 0.f};
  int e = e0;
#pragma unroll 1
  for (; e + 8 <= e1; e += 8) {
    us8 v[4];
#pragma unroll
    for (int j = 0; j < 4; ++j) {
      int s = esrc[e + 2 * j + half];
      v[j] = *(const us8*)&hio[(size_t)s * 256 + ((gi ^ (s & 7)) << 3)];
    }
#pragma unroll
    for (int j = 0; j < 4; ++j)
#pragma unroll
      for (int i = 0; i < 8; ++i) a[i] += bf2f(v[j][i]);
  }
#pragma unroll 1
  for (; e + 2 <= e1; e += 2) {
    int s = esrc[e + half];
    us8 v = *(const us8*)&hio[(size_t)s * 256 + ((gi ^ (s & 7)) << 3)];
#pragma unroll
    for (int i = 0; i < 8; ++i) a[i] += bf2f(v[i]);
  }
  if (e < e1 && half == 0) {
    int s = esrc[e];
    us8 v = *(const us8*)&hio[(size_t)s * 256 + ((gi ^ (s & 7)) << 3)];
#pragma unroll
    for (int i = 0; i < 8; ++i) a[i] += bf2f(v[i]);
  }
  float di = deg_inv[node];
  us8 H;
#pragma unroll
  for (int i = 0; i < 8; ++i) {
    float tot = (a[i] + __shfl_xor(a[i], 32)) * di;
    H[i] = f2bf(tot);
  }
  if (lane < 32)
    *(us8*)&oio[(size_t)node * 256 + ((gi ^ (node & 7)) << 3)] = H;
}

// ---------------- split-bf16 MFMA GEMM ----------------
// out = relu(A1@W1^T + A2@W2^T + b). Tile 128x128, BK=64, 4 waves.
// SA=1 (layer 1): A interleaved [row][hi Kg | lo Kg]; 3 terms (hh, hl, lh).
// SA=0 (layers 2/3): A bf16-hi [row][Kg]; 2 terms (hh, hl).
// Term-major MFMA emission: 16 independent accs between chain reuses.
// mode 0: store h as bf16-hi swizzled (256 ushort rows). mode 1: fp32.

template <int SA>
__global__ __launch_bounds__(256) void k_gemm_mfma(
    const ushort_t* __restrict__ A1, int k1g,
    const ushort_t* __restrict__ w1h, const ushort_t* __restrict__ w1l,
    const ushort_t* __restrict__ A2, int k2g,
    const ushort_t* __restrict__ w2h, const ushort_t* __restrict__ w2l,
    const float* __restrict__ bias, ushort_t* __restrict__ oio,
    float* __restrict__ ofp, int mode) {
  __shared__ __align__(16) ushort_t lds[SA ? 4 : 3][8192];  // A(hi[,lo]), Whi, Wlo

  int t = threadIdx.x;
  int wv = t >> 6, lane = t & 63;
  int wr = wv >> 1, wc = wv & 1;
  int fr = lane & 15, kq = lane >> 4;
  int bm = blockIdx.x, bn = blockIdx.y;
  int rowA0 = bm * 128, rowW0 = bn * 128;

  f32x4 acc[4][4];
#pragma unroll
  for (int m = 0; m < 4; ++m)
#pragma unroll
    for (int n = 0; n < 4; ++n) acc[m][n] = (f32x4)0.f;

  const int ns1 = k1g >> 3, ns2 = k2g >> 3;
  const int lrow = wv * 32 + (lane >> 3);
  const int lj = lane & 7;
  const int WHI = SA ? 2 : 1, WLO = SA ? 3 : 2;

  for (int s = 0; s < ns1 + ns2; ++s) {
    const bool p2 = (s >= ns1);
    const ushort_t* A  = p2 ? A2 : A1;
    const ushort_t* Wh = p2 ? w2h : w1h;
    const ushort_t* Wl = p2 ? w2l : w1l;
    const int Kg = p2 ? k2g : k1g;
    const int ksg = (p2 ? (s - ns1) : s) * 8;

#pragma unroll
    for (int i = 0; i < 4; ++i) {
      int row = lrow + i * 8;
      size_t offA = ((size_t)(rowA0 + row) * (SA ? Kg * 2 : Kg) + ksg + lj) * 8;
      size_t offW = ((size_t)(rowW0 + row) * Kg + ksg + lj) * 8;
      int lo = (wv * 256 + i * 64) * 8;
      gload16(A + offA, &lds[0][lo]);
      if (SA) gload16(A + offA + (size_t)Kg * 8, &lds[1][lo]);
      gload16(Wh + offW, &lds[WHI][lo]);
      gload16(Wl + offW, &lds[WLO][lo]);
    }
    __syncthreads();  // drains vmcnt -> LDS tile ready

#pragma unroll
    for (int kc = 0; kc < 2; ++kc) {
      us8 ah[4], al[4], bh[4], bl[4];
      int kg = kc * 4 + kq;
      int swk = (kg ^ (fr & 7)) << 3;
#pragma unroll
      for (int m = 0; m < 4; ++m) {
        int off = ((wr * 64 + m * 16 + fr) << 6) + swk;
        ah[m] = *(const us8*)&lds[0][off];
        if (SA) al[m] = *(const us8*)&lds[1][off];
      }
#pragma unroll
      for (int n = 0; n < 4; ++n) {
        int off = ((wc * 64 + n * 16 + fr) << 6) + swk;
        bh[n] = *(const us8*)&lds[WHI][off];
        bl[n] = *(const us8*)&lds[WLO][off];
      }
      // term-major: 16 independent MFMAs per term -> no dependent stalls
#pragma unroll
      for (int m = 0; m < 4; ++m)
#pragma unroll
        for (int n = 0; n < 4; ++n)
          acc[m][n] = mfma_bf16(ah[m], bh[n], acc[m][n]);
#pragma unroll
      for (int m = 0; m < 4; ++m)
#pragma unroll
        for (int n = 0; n < 4; ++n)
          acc[m][n] = mfma_bf16(ah[m], bl[n], acc[m][n]);
      if (SA) {
#pragma unroll
        for (int m = 0; m < 4; ++m)
#pragma unroll
          for (int n = 0; n < 4; ++n)
            acc[m][n] = mfma_bf16(al[m], bh[n], acc[m][n]);
      }
    }
    __syncthreads();
  }

  // epilogue: C/D map col=lane&15, row=(lane>>4)*4+reg
#pragma unroll
  for (int n = 0; n < 4; ++n) {
    int colg = bn * 128 + wc * 64 + n * 16 + fr;
    float bv = bias[colg];
#pragma unroll
    for (int m = 0; m < 4; ++m) {
      f32x4 v = acc[m][n];
      int rowb = bm * 128 + wr * 64 + m * 16 + kq * 4;
#pragma unroll
      for (int r = 0; r < 4; ++r) {
        int rowg = rowb + r;
        if (rowg < N_NODES) {
          float h = fmaxf(v[r] + bv, 0.f);
          if (mode == 0) {
            int kbs = ((colg >> 3) ^ (rowg & 7)) << 3;
            oio[(size_t)rowg * 256 + kbs + (colg & 7)] = f2bf(h);
          } else {
            ofp[(size_t)rowg * HID + colg] = h;
          }
        }
      }
    }
  }
}

// ---------------- global mean pool (parallel over graph x chunk) ----------------

__global__ __launch_bounds__(256) void k_pool(const float* __restrict__ h,
                                              const int* __restrict__ gofs,
                                              float* __restrict__ pooled) {
  int g = blockIdx.y, c = blockIdx.x;  // 16 chunks
  int r0 = gofs[g], r1 = gofs[g + 1];
  int rg = threadIdx.x >> 6, lane = threadIdx.x & 63;
  float ax = 0.f, ay = 0.f, az = 0.f, aw = 0.f;
  for (int r = r0 + c * 4 + rg; r < r1; r += 64) {
    float4 v = *(const float4*)&h[(size_t)r * HID + lane * 4];
    ax += v.x; ay += v.y; az += v.z; aw += v.w;
  }
  __shared__ float4 sm[4][64];
  sm[rg][lane] = make_float4(ax, ay, az, aw);
  __syncthreads();
  if (rg == 0) {
    float4 s0 = sm[0][lane], s1 = sm[1][lane], s2 = sm[2][lane], s3 = sm[3][lane];
    float* p = &pooled[g * HID + lane * 4];
    atomicAdd(p + 0, s0.x + s1.x + s2.x + s3.x);
    atomicAdd(p + 1, s0.y + s1.y + s2.y + s3.y);
    atomicAdd(p + 2, s0.z + s1.z + s2.z + s3.z);
    atomicAdd(p + 3, s0.w + s1.w + s2.w + s3.w);
  }
}

// ---------------- head ----------------

__global__ __launch_bounds__(128) void k_head(const float* __restrict__ pooled,
                                              const int* __restrict__ gofs,
                                              const float* __restrict__ w1,
                                              const float* __restrict__ b1,
                                              const float* __restrict__ w2,
                                              const float* __restrict__ b2,
                                              float* __restrict__ out) {
  __shared__ float p[HID];
  __shared__ float g1[HID / 2];
  int g = blockIdx.x, t = threadIdx.x;
  float inv = 1.f / fmaxf((float)(gofs[g + 1] - gofs[g]), 1.f);
  p[t] = pooled[g * HID + t] * inv;
  p[t + 128] = pooled[g * HID + 128 + t] * inv;
  __syncthreads();
  float s = b1[t];
#pragma unroll 4
  for (int k = 0; k < HID; ++k) s = fmaf(p[k], w1[t * HID + k], s);
  g1[t] = fmaxf(s, 0.f);
  __syncthreads();
  if (t < N_OUT) {
    float s2 = b2[t];
#pragma unroll 4
    for (int k = 0; k < HID / 2; ++k) s2 = fmaf(g1[k], w2[t * (HID / 2) + k], s2);
    out[g * N_OUT + t] = s2;
  }
}

// ---------------- launch ----------------

extern "C" void kernel_launch(void* const* d_in, const int* in_sizes, int n_in,
                              void* d_out, int out_size, void* d_ws, size_t ws_size,
                              hipStream_t stream) {
  const float* x      = (const float*)d_in[0];
  const int*   ei     = (const int*)d_in[1];
  const int*   batch  = (const int*)d_in[2];
  const float* w1lw   = (const float*)d_in[3];
  const float* b1     = (const float*)d_in[4];
  const float* w1rw   = (const float*)d_in[5];
  const float* w2lw   = (const float*)d_in[6];
  const float* b2     = (const float*)d_in[7];
  const float* w2rw   = (const float*)d_in[8];
  const float* w3lw   = (const float*)d_in[9];
  const float* b3     = (const float*)d_in[10];
  const float* w3rw   = (const float*)d_in[11];
  const float* lin1_w = (const float*)d_in[12];
  const float* lin1_b = (const float*)d_in[13];
  const float* lin2_w = (const float*)d_in[14];
  const float* lin2_b = (const float*)d_in[15];
  float* out = (float*)d_out;

  const int* srcIdx = ei;
  const int* dstIdx = ei + N_EDGES;

  size_t off = 0;
  auto carve = [&](size_t bytes) {
    size_t r = off;
    off += (bytes + 255) & ~(size_t)255;
    return r;
  };
  char* ws = (char*)d_ws;
  int*      deg_priv = (int*)(ws + carve((size_t)8 * N_NODES * 4));
  int*      deg      = (int*)(ws + carve((size_t)N_NODES * 4));
  int*      rank     = (int*)(ws + carve((size_t)N_EDGES * 4));
  int*      rowptr   = (int*)(ws + carve((size_t)(N_NODES + 1) * 4));
  float*    deg_inv  = (float*)(ws + carve((size_t)N_NODES * 4));
  int*      esrc     = (int*)(ws + carve((size_t)N_EDGES * 4));
  int*      partial  = (int*)(ws + carve(64 * 4));
  int*      gofs     = (int*)(ws + carve((N_GRAPHS + 1) * 4));
  ushort_t* xio      = (ushort_t*)(ws + carve((size_t)M_PAD * 128 * 2));  // x split Kg=8
  ushort_t* agg1     = (ushort_t*)(ws + carve((size_t)M_PAD * 128 * 2));  // layer-1 agg split
  ushort_t* agg      = (ushort_t*)(ws + carve((size_t)M_PAD * 256 * 2));  // layers-2/3 agg hi
  char*     h1blk    = ws + carve((size_t)M_PAD * HID * 4);  // h1 bf16-hi OR h3 fp32
  ushort_t* h1       = (ushort_t*)h1blk;
  float*    h3       = (float*)h1blk;  // alias: h1 dead before gemm3 writes
  ushort_t* h2       = (ushort_t*)(ws + carve((size_t)M_PAD * 256 * 2));
  ushort_t* w1hi     = (ushort_t*)(ws + carve((size_t)2 * 256 * F_IN * 2));
  ushort_t* w1lo     = (ushort_t*)(ws + carve((size_t)2 * 256 * F_IN * 2));
  ushort_t* w2hi     = (ushort_t*)(ws + carve((size_t)2 * 256 * HID * 2));
  ushort_t* w2lo     = (ushort_t*)(ws + carve((size_t)2 * 256 * HID * 2));
  ushort_t* w3hi     = (ushort_t*)(ws + carve((size_t)2 * 256 * HID * 2));
  ushort_t* w3lo     = (ushort_t*)(ws + carve((size_t)2 * 256 * HID * 2));
  float*    pooled   = (float*)(ws + carve((size_t)N_GRAPHS * HID * 4));
  (void)ws_size; (void)n_in; (void)in_sizes; (void)out_size;

  hipMemsetAsync(deg_priv, 0, (size_t)8 * N_NODES * 4, stream);
  hipMemsetAsync(pooled, 0, (size_t)N_GRAPHS * HID * 4, stream);

  const int EB = (N_EDGES + 255) / 256;
  const int SB = (N_NODES + 1023) / 1024;

  k_hist<<<EB, 256, 0, stream>>>(dstIdx, deg_priv, rank);
  k_gofs<<<1, 256, 0, stream>>>(batch, gofs);
  k_scan1<<<SB, 1024, 0, stream>>>(deg_priv, deg, rowptr, partial);
  k_scan2<<<1, 64, 0, stream>>>(partial, rowptr);
  k_scan3<<<SB, 1024, 0, stream>>>(deg, partial, rowptr, deg_inv);
  k_place<<<EB, 256, 0, stream>>>(srcIdx, dstIdx, rowptr, deg_priv, rank, esrc);

  k_prep_x<<<(N_NODES * 8 + 255) / 256, 256, 0, stream>>>(x, xio);
  k_prep_w<<<dim3(32, 2, 3), 256, 0, stream>>>(w1lw, w1rw, w2lw, w2rw, w3lw, w3rw,
                                               w1hi, w1lo, w2hi, w2lo, w3hi, w3lo);

  dim3 ggrid((N_NODES + 127) / 128, 2);
  const int AB = N_NODES / 4;

  // layer 1 (3-term split A)
  k_agg64s<<<AB, 256, 0, stream>>>(x, rowptr, esrc, deg_inv, agg1);
  k_gemm_mfma<1><<<ggrid, 256, 0, stream>>>(agg1, 8, w1hi, w1lo,
                                            xio, 8, w1hi + 256 * F_IN, w1lo + 256 * F_IN,
                                            b1, h1, nullptr, 0);
  // layer 2 (A hi-only, 2-term)
  k_agg256s<<<AB, 256, 0, stream>>>(h1, rowptr, esrc, deg_inv, agg);
  k_gemm_mfma<0><<<ggrid, 256, 0, stream>>>(agg, 32, w2hi, w2lo,
                                            h1, 32, w2hi + 256 * HID, w2lo + 256 * HID,
                                            b2, h2, nullptr, 0);
  // layer 3 (fp32 out for pooling; h3 aliases dead h1)
  k_agg256s<<<AB, 256, 0, stream>>>(h2, rowptr, esrc, deg_inv, agg);
  k_gemm_mfma<0><<<ggrid, 256, 0, stream>>>(agg, 32, w3hi, w3lo,
                                            h2, 32, w3hi + 256 * HID, w3lo + 256 * HID,
                                            b3, nullptr, h3, 1);

  k_pool<<<dim3(16, N_GRAPHS), 256, 0, stream>>>(h3, gofs, pooled);
  k_head<<<N_GRAPHS, 128, 0, stream>>>(pooled, gofs, lin1_w, lin1_b, lin2_w, lin2_b, out);
}

// Round 8
// 394.247 us; speedup vs baseline: 3.0500x; 1.0004x over previous
//
#include <hip/hip_runtime.h>

#define N_NODES 50000
#define M_PAD   50048   // padded rows so global_load_lds never reads past buffers
#define N_EDGES 800000
#define F_IN 64
#define HID 256
#define N_GRAPHS 128
#define N_OUT 24

typedef unsigned short ushort_t;
typedef __attribute__((ext_vector_type(8))) unsigned short us8;
typedef __attribute__((ext_vector_type(8))) __bf16 bf16x8;
typedef __attribute__((ext_vector_type(4))) float f32x4;

__device__ __forceinline__ unsigned short f2bf(float f) {
  unsigned u = __builtin_bit_cast(unsigned, f);
  return (unsigned short)((u + 0x7fffu + ((u >> 16) & 1u)) >> 16);
}
__device__ __forceinline__ float bf2f(unsigned short h) {
  return __builtin_bit_cast(float, (unsigned)h << 16);
}

__device__ __forceinline__ f32x4 mfma_bf16(us8 a, us8 b, f32x4 c) {
  return __builtin_amdgcn_mfma_f32_16x16x32_bf16(
      __builtin_bit_cast(bf16x8, a), __builtin_bit_cast(bf16x8, b), c, 0, 0, 0);
}

__device__ __forceinline__ void gload16(const ushort_t* g, ushort_t* l) {
  __builtin_amdgcn_global_load_lds(
      (const __attribute__((address_space(1))) void*)g,
      (__attribute__((address_space(3))) void*)l, 16, 0, 0);
}

// ---------------- CSR build (privatized histogram, atomic-free scatter) ----------------

__global__ void k_hist(const int* __restrict__ dst, int* __restrict__ deg_priv,
                       int* __restrict__ rank) {
  int e = blockIdx.x * 256 + threadIdx.x;
  if (e < N_EDGES) {
    int c = blockIdx.x & 7;
    rank[e] = atomicAdd(&deg_priv[c * N_NODES + dst[e]], 1);
  }
}

// batch is sorted: gofs[g] = first index with batch[i] >= g (binary search).
__global__ void k_gofs(const int* __restrict__ batch, int* __restrict__ gofs) {
  int t = threadIdx.x;
  if (t > N_GRAPHS) return;
  int lo = 0, hi = N_NODES;
  while (lo < hi) {
    int mid = (lo + hi) >> 1;
    if (batch[mid] < t) lo = mid + 1;
    else hi = mid;
  }
  gofs[t] = lo;
}

__global__ __launch_bounds__(1024) void k_scan1(int* __restrict__ deg_priv,
                                                int* __restrict__ deg,
                                                int* __restrict__ rowptr,
                                                int* __restrict__ partial) {
  __shared__ int s[1024];
  int t = threadIdx.x;
  int idx = blockIdx.x * 1024 + t;
  int v = 0;
  if (idx < N_NODES) {
    int run = 0;
#pragma unroll
    for (int c = 0; c < 8; ++c) {
      int dv = deg_priv[c * N_NODES + idx];
      deg_priv[c * N_NODES + idx] = run;  // exclusive offset among copies
      run += dv;
    }
    deg[idx] = run;
    v = run;
  }
  s[t] = v;
  __syncthreads();
  for (int off = 1; off < 1024; off <<= 1) {
    int a = (t >= off) ? s[t - off] : 0;
    __syncthreads();
    s[t] += a;
    __syncthreads();
  }
  if (idx < N_NODES) rowptr[idx] = s[t] - v;  // local exclusive
  if (t == 1023) partial[blockIdx.x] = s[1023];
}

__global__ void k_scan2(int* __restrict__ partial, int* __restrict__ rowptr) {
  __shared__ int s[64];
  int t = threadIdx.x;
  const int NB = (N_NODES + 1023) / 1024;
  int v = (t < NB) ? partial[t] : 0;
  s[t] = v;
  __syncthreads();
  for (int off = 1; off < 64; off <<= 1) {
    int a = (t >= off) ? s[t - off] : 0;
    __syncthreads();
    s[t] += a;
    __syncthreads();
  }
  if (t < NB) partial[t] = s[t] - v;
  if (t == NB - 1) rowptr[N_NODES] = s[t];
}

__global__ __launch_bounds__(1024) void k_scan3(const int* __restrict__ deg,
                                                const int* __restrict__ partial,
                                                int* __restrict__ rowptr,
                                                float* __restrict__ deg_inv) {
  int idx = blockIdx.x * 1024 + threadIdx.x;
  if (idx < N_NODES) {
    rowptr[idx] += partial[blockIdx.x];
    deg_inv[idx] = 1.0f / fmaxf((float)deg[idx], 1.0f);
  }
}

__global__ void k_place(const int* __restrict__ src, const int* __restrict__ dst,
                        const int* __restrict__ rowptr, const int* __restrict__ deg_priv,
                        const int* __restrict__ rank, int* __restrict__ esrc) {
  int e = blockIdx.x * 256 + threadIdx.x;
  if (e < N_EDGES) {
    int c = blockIdx.x & 7;
    int d = dst[e];
    esrc[rowptr[d] + deg_priv[c * N_NODES + d] + rank[e]] = src[e];
  }
}

// ---------------- split/swizzle prep ----------------
// x: interleaved [hi 8 granules | lo 8 granules]; granule kb at slot kb^(row&7).

__global__ void k_prep_x(const float* __restrict__ x, ushort_t* __restrict__ xio) {
  int g = blockIdx.x * 256 + threadIdx.x;
  if (g >= N_NODES * 8) return;
  int row = g >> 3, kb = g & 7;
  const float* p = x + (size_t)row * F_IN + kb * 8;
  us8 H, L;
#pragma unroll
  for (int i = 0; i < 8; ++i) {
    float f = p[i];
    unsigned short hi = f2bf(f);
    H[i] = hi;
    L[i] = f2bf(f - bf2f(hi));
  }
  size_t ob = (size_t)row * 128 + (size_t)((kb ^ (row & 7)) << 3);
  *(us8*)&xio[ob] = H;
  *(us8*)&xio[ob + 64] = L;
}

// all three layers' weights; W kept as separate hi/lo arrays (side-major).
__global__ void k_prep_w(const float* __restrict__ w1lp, const float* __restrict__ w1rp,
                         const float* __restrict__ w2lp, const float* __restrict__ w2rp,
                         const float* __restrict__ w3lp, const float* __restrict__ w3rp,
                         ushort_t* __restrict__ w1h, ushort_t* __restrict__ w1l,
                         ushort_t* __restrict__ w2h, ushort_t* __restrict__ w2l,
                         ushort_t* __restrict__ w3h, ushort_t* __restrict__ w3l) {
  int layer = blockIdx.z, side = blockIdx.y;
  const int Kg = (layer == 0) ? 8 : 32;
  int g = blockIdx.x * 256 + threadIdx.x;
  if (g >= 256 * Kg) return;
  const float* src = (layer == 0) ? (side ? w1rp : w1lp)
                   : (layer == 1) ? (side ? w2rp : w2lp)
                                  : (side ? w3rp : w3lp);
  ushort_t* dh = (layer == 0) ? w1h : (layer == 1) ? w2h : w3h;
  ushort_t* dl = (layer == 0) ? w1l : (layer == 1) ? w2l : w3l;
  int row = g / Kg, kb = g % Kg;
  const float* p = src + (size_t)row * (Kg * 8) + kb * 8;
  us8 H, L;
#pragma unroll
  for (int i = 0; i < 8; ++i) {
    float f = p[i];
    unsigned short hi = f2bf(f);
    H[i] = hi;
    L[i] = f2bf(f - bf2f(hi));
  }
  size_t ob = ((size_t)(side * 256 + row) * Kg + (kb ^ (row & 7))) * 8;
  *(us8*)&dh[ob] = H;
  *(us8*)&dl[ob] = L;
}

// ---------------- aggregation (gather over CSR) ----------------

// layer-1 agg: fp32 x gather -> split hi/lo interleaved (Kg=8) for 3-term GEMM.
__global__ __launch_bounds__(256) void k_agg64s(const float* __restrict__ x,
                                                const int* __restrict__ rowptr,
                                                const int* __restrict__ esrc,
                                                const float* __restrict__ deg_inv,
                                                ushort_t* __restrict__ oio) {
  int node = blockIdx.x * 4 + (threadIdx.x >> 6);
  if (node >= N_NODES) return;
  int lane = threadIdx.x & 63;
  int e0 = rowptr[node], e1 = rowptr[node + 1];
  float acc = 0.f;
  int e = e0;
  for (; e + 4 <= e1; e += 4) {
    int s0 = esrc[e], s1 = esrc[e + 1], s2 = esrc[e + 2], s3 = esrc[e + 3];
    float v0 = x[(size_t)s0 * F_IN + lane];
    float v1 = x[(size_t)s1 * F_IN + lane];
    float v2 = x[(size_t)s2 * F_IN + lane];
    float v3 = x[(size_t)s3 * F_IN + lane];
    acc += v0 + v1 + v2 + v3;
  }
  for (; e < e1; ++e) acc += x[(size_t)esrc[e] * F_IN + lane];
  acc *= deg_inv[node];
  unsigned short hi = f2bf(acc);
  unsigned short lo = f2bf(acc - bf2f(hi));
  size_t rb = (size_t)node * 128;
  int slot = ((lane >> 3) ^ (node & 7)) << 3;
  oio[rb + slot + (lane & 7)] = hi;
  oio[rb + 64 + slot + (lane & 7)] = lo;
}

// layers 2/3: h rows are plain bf16-hi, 256 ushort (32 swizzled granules).
// Half-wave per edge (32 lanes x 16B = 512B row); combine halves via shfl.
__global__ __launch_bounds__(256) void k_agg256s(const ushort_t* __restrict__ hio,
                                                 const int* __restrict__ rowptr,
                                                 const int* __restrict__ esrc,
                                                 const float* __restrict__ deg_inv,
                                                 ushort_t* __restrict__ oio) {
  int node = blockIdx.x * 4 + (threadIdx.x >> 6);
  if (node >= N_NODES) return;
  int lane = threadIdx.x & 63;
  int gi = lane & 31;       // granule within row
  int half = lane >> 5;     // 0: even edges, 1: odd edges
  int e0 = rowptr[node], e1 = rowptr[node + 1];
  float a[8] = {0.f, 0.f, 0.f, 0.f, 0.f, 0.f, 0.f, 0.f};
  int e = e0;
#pragma unroll 1
  for (; e + 8 <= e1; e += 8) {
    us8 v[4];
#pragma unroll
    for (int j = 0; j < 4; ++j) {
      int s = esrc[e + 2 * j + half];
      v[j] = *(const us8*)&hio[(size_t)s * 256 + ((gi ^ (s & 7)) << 3)];
    }
#pragma unroll
    for (int j = 0; j < 4; ++j)
#pragma unroll
      for (int i = 0; i < 8; ++i) a[i] += bf2f(v[j][i]);
  }
#pragma unroll 1
  for (; e + 2 <= e1; e += 2) {
    int s = esrc[e + half];
    us8 v = *(const us8*)&hio[(size_t)s * 256 + ((gi ^ (s & 7)) << 3)];
#pragma unroll
    for (int i = 0; i < 8; ++i) a[i] += bf2f(v[i]);
  }
  if (e < e1 && half == 0) {
    int s = esrc[e];
    us8 v = *(const us8*)&hio[(size_t)s * 256 + ((gi ^ (s & 7)) << 3)];
#pragma unroll
    for (int i = 0; i < 8; ++i) a[i] += bf2f(v[i]);
  }
  float di = deg_inv[node];
  us8 H;
#pragma unroll
  for (int i = 0; i < 8; ++i) {
    float tot = (a[i] + __shfl_xor(a[i], 32)) * di;
    H[i] = f2bf(tot);
  }
  if (lane < 32)
    *(us8*)&oio[(size_t)node * 256 + ((gi ^ (node & 7)) << 3)] = H;
}

// ---------------- split-bf16 MFMA GEMM ----------------
// out = relu(A1@W1^T + A2@W2^T + b). Tile 128x128, BK=64, 4 waves.
// SA=1 (layer 1): A interleaved [row][hi Kg | lo Kg]; 3 terms (hh, hl, lh).
// SA=0 (layers 2/3): A bf16-hi [row][Kg]; 2 terms (hh, hl).
// Term-major MFMA emission: 16 independent accs between chain reuses.
// mode 0: store h as bf16-hi swizzled (256 ushort rows). mode 1: fp32.

template <int SA>
__global__ __launch_bounds__(256) void k_gemm_mfma(
    const ushort_t* __restrict__ A1, int k1g,
    const ushort_t* __restrict__ w1h, const ushort_t* __restrict__ w1l,
    const ushort_t* __restrict__ A2, int k2g,
    const ushort_t* __restrict__ w2h, const ushort_t* __restrict__ w2l,
    const float* __restrict__ bias, ushort_t* __restrict__ oio,
    float* __restrict__ ofp, int mode) {
  __shared__ __align__(16) ushort_t lds[SA ? 4 : 3][8192];  // A(hi[,lo]), Whi, Wlo

  int t = threadIdx.x;
  int wv = t >> 6, lane = t & 63;
  int wr = wv >> 1, wc = wv & 1;
  int fr = lane & 15, kq = lane >> 4;
  int bm = blockIdx.x, bn = blockIdx.y;
  int rowA0 = bm * 128, rowW0 = bn * 128;

  f32x4 acc[4][4];
#pragma unroll
  for (int m = 0; m < 4; ++m)
#pragma unroll
    for (int n = 0; n < 4; ++n) acc[m][n] = (f32x4)0.f;

  const int ns1 = k1g >> 3, ns2 = k2g >> 3;
  const int lrow = wv * 32 + (lane >> 3);
  const int lj = lane & 7;
  const int WHI = SA ? 2 : 1, WLO = SA ? 3 : 2;

  for (int s = 0; s < ns1 + ns2; ++s) {
    const bool p2 = (s >= ns1);
    const ushort_t* A  = p2 ? A2 : A1;
    const ushort_t* Wh = p2 ? w2h : w1h;
    const ushort_t* Wl = p2 ? w2l : w1l;
    const int Kg = p2 ? k2g : k1g;
    const int ksg = (p2 ? (s - ns1) : s) * 8;

#pragma unroll
    for (int i = 0; i < 4; ++i) {
      int row = lrow + i * 8;
      size_t offA = ((size_t)(rowA0 + row) * (SA ? Kg * 2 : Kg) + ksg + lj) * 8;
      size_t offW = ((size_t)(rowW0 + row) * Kg + ksg + lj) * 8;
      int lo = (wv * 256 + i * 64) * 8;
      gload16(A + offA, &lds[0][lo]);
      if (SA) gload16(A + offA + (size_t)Kg * 8, &lds[1][lo]);
      gload16(Wh + offW, &lds[WHI][lo]);
      gload16(Wl + offW, &lds[WLO][lo]);
    }
    __syncthreads();  // drains vmcnt -> LDS tile ready

#pragma unroll
    for (int kc = 0; kc < 2; ++kc) {
      us8 ah[4], al[4], bh[4], bl[4];
      int kg = kc * 4 + kq;
      int swk = (kg ^ (fr & 7)) << 3;
#pragma unroll
      for (int m = 0; m < 4; ++m) {
        int off = ((wr * 64 + m * 16 + fr) << 6) + swk;
        ah[m] = *(const us8*)&lds[0][off];
        if (SA) al[m] = *(const us8*)&lds[1][off];
      }
#pragma unroll
      for (int n = 0; n < 4; ++n) {
        int off = ((wc * 64 + n * 16 + fr) << 6) + swk;
        bh[n] = *(const us8*)&lds[WHI][off];
        bl[n] = *(const us8*)&lds[WLO][off];
      }
      // term-major: 16 independent MFMAs per term -> no dependent stalls
#pragma unroll
      for (int m = 0; m < 4; ++m)
#pragma unroll
        for (int n = 0; n < 4; ++n)
          acc[m][n] = mfma_bf16(ah[m], bh[n], acc[m][n]);
#pragma unroll
      for (int m = 0; m < 4; ++m)
#pragma unroll
        for (int n = 0; n < 4; ++n)
          acc[m][n] = mfma_bf16(ah[m], bl[n], acc[m][n]);
      if (SA) {
#pragma unroll
        for (int m = 0; m < 4; ++m)
#pragma unroll
          for (int n = 0; n < 4; ++n)
            acc[m][n] = mfma_bf16(al[m], bh[n], acc[m][n]);
      }
    }
    __syncthreads();
  }

  // epilogue: C/D map col=lane&15, row=(lane>>4)*4+reg
#pragma unroll
  for (int n = 0; n < 4; ++n) {
    int colg = bn * 128 + wc * 64 + n * 16 + fr;
    float bv = bias[colg];
#pragma unroll
    for (int m = 0; m < 4; ++m) {
      f32x4 v = acc[m][n];
      int rowb = bm * 128 + wr * 64 + m * 16 + kq * 4;
#pragma unroll
      for (int r = 0; r < 4; ++r) {
        int rowg = rowb + r;
        if (rowg < N_NODES) {
          float h = fmaxf(v[r] + bv, 0.f);
          if (mode == 0) {
            int kbs = ((colg >> 3) ^ (rowg & 7)) << 3;
            oio[(size_t)rowg * 256 + kbs + (colg & 7)] = f2bf(h);
          } else {
            ofp[(size_t)rowg * HID + colg] = h;
          }
        }
      }
    }
  }
}

// ---------------- global mean pool (parallel over graph x chunk) ----------------

__global__ __launch_bounds__(256) void k_pool(const float* __restrict__ h,
                                              const int* __restrict__ gofs,
                                              float* __restrict__ pooled) {
  int g = blockIdx.y, c = blockIdx.x;  // 16 chunks
  int r0 = gofs[g], r1 = gofs[g + 1];
  int rg = threadIdx.x >> 6, lane = threadIdx.x & 63;
  float ax = 0.f, ay = 0.f, az = 0.f, aw = 0.f;
  for (int r = r0 + c * 4 + rg; r < r1; r += 64) {
    float4 v = *(const float4*)&h[(size_t)r * HID + lane * 4];
    ax += v.x; ay += v.y; az += v.z; aw += v.w;
  }
  __shared__ float4 sm[4][64];
  sm[rg][lane] = make_float4(ax, ay, az, aw);
  __syncthreads();
  if (rg == 0) {
    float4 s0 = sm[0][lane], s1 = sm[1][lane], s2 = sm[2][lane], s3 = sm[3][lane];
    float* p = &pooled[g * HID + lane * 4];
    atomicAdd(p + 0, s0.x + s1.x + s2.x + s3.x);
    atomicAdd(p + 1, s0.y + s1.y + s2.y + s3.y);
    atomicAdd(p + 2, s0.z + s1.z + s2.z + s3.z);
    atomicAdd(p + 3, s0.w + s1.w + s2.w + s3.w);
  }
}

// ---------------- head ----------------

__global__ __launch_bounds__(128) void k_head(const float* __restrict__ pooled,
                                              const int* __restrict__ gofs,
                                              const float* __restrict__ w1,
                                              const float* __restrict__ b1,
                                              const float* __restrict__ w2,
                                              const float* __restrict__ b2,
                                              float* __restrict__ out) {
  __shared__ float p[HID];
  __shared__ float g1[HID / 2];
  int g = blockIdx.x, t = threadIdx.x;
  float inv = 1.f / fmaxf((float)(gofs[g + 1] - gofs[g]), 1.f);
  p[t] = pooled[g * HID + t] * inv;
  p[t + 128] = pooled[g * HID + 128 + t] * inv;
  __syncthreads();
  float s = b1[t];
#pragma unroll 4
  for (int k = 0; k < HID; ++k) s = fmaf(p[k], w1[t * HID + k], s);
  g1[t] = fmaxf(s, 0.f);
  __syncthreads();
  if (t < N_OUT) {
    float s2 = b2[t];
#pragma unroll 4
    for (int k = 0; k < HID / 2; ++k) s2 = fmaf(g1[k], w2[t * (HID / 2) + k], s2);
    out[g * N_OUT + t] = s2;
  }
}

// ---------------- launch ----------------

extern "C" void kernel_launch(void* const* d_in, const int* in_sizes, int n_in,
                              void* d_out, int out_size, void* d_ws, size_t ws_size,
                              hipStream_t stream) {
  const float* x      = (const float*)d_in[0];
  const int*   ei     = (const int*)d_in[1];
  const int*   batch  = (const int*)d_in[2];
  const float* w1lw   = (const float*)d_in[3];
  const float* b1     = (const float*)d_in[4];
  const float* w1rw   = (const float*)d_in[5];
  const float* w2lw   = (const float*)d_in[6];
  const float* b2     = (const float*)d_in[7];
  const float* w2rw   = (const float*)d_in[8];
  const float* w3lw   = (const float*)d_in[9];
  const float* b3     = (const float*)d_in[10];
  const float* w3rw   = (const float*)d_in[11];
  const float* lin1_w = (const float*)d_in[12];
  const float* lin1_b = (const float*)d_in[13];
  const float* lin2_w = (const float*)d_in[14];
  const float* lin2_b = (const float*)d_in[15];
  float* out = (float*)d_out;

  const int* srcIdx = ei;
  const int* dstIdx = ei + N_EDGES;

  size_t off = 0;
  auto carve = [&](size_t bytes) {
    size_t r = off;
    off += (bytes + 255) & ~(size_t)255;
    return r;
  };
  char* ws = (char*)d_ws;
  int*      deg_priv = (int*)(ws + carve((size_t)8 * N_NODES * 4));
  int*      deg      = (int*)(ws + carve((size_t)N_NODES * 4));
  int*      rank     = (int*)(ws + carve((size_t)N_EDGES * 4));
  int*      rowptr   = (int*)(ws + carve((size_t)(N_NODES + 1) * 4));
  float*    deg_inv  = (float*)(ws + carve((size_t)N_NODES * 4));
  int*      esrc     = (int*)(ws + carve((size_t)N_EDGES * 4));
  int*      partial  = (int*)(ws + carve(64 * 4));
  int*      gofs     = (int*)(ws + carve((N_GRAPHS + 1) * 4));
  ushort_t* xio      = (ushort_t*)(ws + carve((size_t)M_PAD * 128 * 2));  // x split Kg=8
  ushort_t* agg1     = (ushort_t*)(ws + carve((size_t)M_PAD * 128 * 2));  // layer-1 agg split
  ushort_t* agg      = (ushort_t*)(ws + carve((size_t)M_PAD * 256 * 2));  // layers-2/3 agg hi
  char*     h1blk    = ws + carve((size_t)M_PAD * HID * 4);  // h1 bf16-hi OR h3 fp32
  ushort_t* h1       = (ushort_t*)h1blk;
  float*    h3       = (float*)h1blk;  // alias: h1 dead before gemm3 writes
  ushort_t* h2       = (ushort_t*)(ws + carve((size_t)M_PAD * 256 * 2));
  ushort_t* w1hi     = (ushort_t*)(ws + carve((size_t)2 * 256 * F_IN * 2));
  ushort_t* w1lo     = (ushort_t*)(ws + carve((size_t)2 * 256 * F_IN * 2));
  ushort_t* w2hi     = (ushort_t*)(ws + carve((size_t)2 * 256 * HID * 2));
  ushort_t* w2lo     = (ushort_t*)(ws + carve((size_t)2 * 256 * HID * 2));
  ushort_t* w3hi     = (ushort_t*)(ws + carve((size_t)2 * 256 * HID * 2));
  ushort_t* w3lo     = (ushort_t*)(ws + carve((size_t)2 * 256 * HID * 2));
  float*    pooled   = (float*)(ws + carve((size_t)N_GRAPHS * HID * 4));
  (void)ws_size; (void)n_in; (void)in_sizes; (void)out_size;

  hipMemsetAsync(deg_priv, 0, (size_t)8 * N_NODES * 4, stream);
  hipMemsetAsync(pooled, 0, (size_t)N_GRAPHS * HID * 4, stream);

  const int EB = (N_EDGES + 255) / 256;
  const int SB = (N_NODES + 1023) / 1024;

  k_hist<<<EB, 256, 0, stream>>>(dstIdx, deg_priv, rank);
  k_gofs<<<1, 256, 0, stream>>>(batch, gofs);
  k_scan1<<<SB, 1024, 0, stream>>>(deg_priv, deg, rowptr, partial);
  k_scan2<<<1, 64, 0, stream>>>(partial, rowptr);
  k_scan3<<<SB, 1024, 0, stream>>>(deg, partial, rowptr, deg_inv);
  k_place<<<EB, 256, 0, stream>>>(srcIdx, dstIdx, rowptr, deg_priv, rank, esrc);

  k_prep_x<<<(N_NODES * 8 + 255) / 256, 256, 0, stream>>>(x, xio);
  k_prep_w<<<dim3(32, 2, 3), 256, 0, stream>>>(w1lw, w1rw, w2lw, w2rw, w3lw, w3rw,
                                               w1hi, w1lo, w2hi, w2lo, w3hi, w3lo);

  dim3 ggrid((N_NODES + 127) / 128, 2);
  const int AB = N_NODES / 4;

  // layer 1 (3-term split A)
  k_agg64s<<<AB, 256, 0, stream>>>(x, rowptr, esrc, deg_inv, agg1);
  k_gemm_mfma<1><<<ggrid, 256, 0, stream>>>(agg1, 8, w1hi, w1lo,
                                            xio, 8, w1hi + 256 * F_IN, w1lo + 256 * F_IN,
                                            b1, h1, nullptr, 0);
  // layer 2 (A hi-only, 2-term)
  k_agg256s<<<AB, 256, 0, stream>>>(h1, rowptr, esrc, deg_inv, agg);
  k_gemm_mfma<0><<<ggrid, 256, 0, stream>>>(agg, 32, w2hi, w2lo,
                                            h1, 32, w2hi + 256 * HID, w2lo + 256 * HID,
                                            b2, h2, nullptr, 0);
  // layer 3 (fp32 out for pooling; h3 aliases dead h1)
  k_agg256s<<<AB, 256, 0, stream>>>(h2, rowptr, esrc, deg_inv, agg);
  k_gemm_mfma<0><<<ggrid, 256, 0, stream>>>(agg, 32, w3hi, w3lo,
                                            h2, 32, w3hi + 256 * HID, w3lo + 256 * HID,
                                            b3, nullptr, h3, 1);

  k_pool<<<dim3(16, N_GRAPHS), 256, 0, stream>>>(h3, gofs, pooled);
  k_head<<<N_GRAPHS, 128, 0, stream>>>(pooled, gofs, lin1_w, lin1_b, lin2_w, lin2_b, out);
}